// Round 4
// baseline (683.547 us; speedup 1.0000x reference)
//
#include <hip/hip_runtime.h>
#include <hip/hip_bf16.h>

#define BB 16
#define LL 1024
#define EE 128
#define HH 4
#define DD 128
#define NN 1025
#define HE 512
#define AL 0.2f
#define EPSV 1e-6f
#define SS 8
#define CC 128
#define C1 129

// workspace float offsets (footprint unchanged; Tot* alias enc4 region — dead
// before k_row writes enc4). Upart sized for 32 chunks (exactly fills to O_JS).
#define O_WH   0
#define O_F1   524800
#define O_F2   528900
#define O_ELO  537096
#define O_EHI  541192
#define O_EF1H 545288
#define O_EF1L 549384
#define O_W2   553480
#define O_SLO  555528
#define O_SHI  1612296
#define O_SLOS 2669064
#define O_SHIS 2677320
#define O_WR   2685576
#define O_UP   2751112
#define O_JS   3799688
#define O_PS   3803784
#define O_E4   3807880
#define O_TLO  3807880
#define O_THI  4864648
#define O_TLOS 5921416
#define O_THIS 5929672
#define O_CNT  6000000   // 64 scan counters + 16 acc counters (zeroed by k_rankw2)

// ---- K1: Wh + f1/f2 + exp tables; 4 rows/block for W_enc L2 reuse ---------
__global__ void VGNN_27049704030896_kernel(const float* __restrict__ embed,
                                           const float* __restrict__ W_enc,
                                           const float* __restrict__ a_src,
                                           const float* __restrict__ a_dst,
                                           float* __restrict__ Wh,
                                           float* __restrict__ f1,
                                           float* __restrict__ f2,
                                           float* __restrict__ ef1hi,
                                           float* __restrict__ ef1lo) {
  __shared__ float red[8][EE];
  int n0 = blockIdx.x * 4;
  int h = blockIdx.y;
  int f = threadIdx.x;   // 128
  const float* ep0 = embed + (long)((n0 + 0 < NN) ? n0 + 0 : NN - 1) * EE;
  const float* ep1 = embed + (long)((n0 + 1 < NN) ? n0 + 1 : NN - 1) * EE;
  const float* ep2 = embed + (long)((n0 + 2 < NN) ? n0 + 2 : NN - 1) * EE;
  const float* ep3 = embed + (long)((n0 + 3 < NN) ? n0 + 3 : NN - 1) * EE;
  float m0 = (n0 + 0 > 0 && n0 + 0 < NN) ? 1.0f : 0.0f;
  float m1 = (n0 + 1 > 0 && n0 + 1 < NN) ? 1.0f : 0.0f;
  float m2 = (n0 + 2 > 0 && n0 + 2 < NN) ? 1.0f : 0.0f;
  float m3 = (n0 + 3 > 0 && n0 + 3 < NN) ? 1.0f : 0.0f;
  float a0 = 0.0f, a1 = 0.0f, a2 = 0.0f, a3 = 0.0f;
  for (int e = 0; e < EE; e++) {
    float wv = W_enc[((long)(h * EE + e)) * EE + f];
    a0 += ep0[e] * wv; a1 += ep1[e] * wv;
    a2 += ep2[e] * wv; a3 += ep3[e] * wv;
  }
  a0 *= m0; a1 *= m1; a2 *= m2; a3 *= m3;
  if (n0 + 0 < NN) Wh[((long)(h * NN + n0 + 0)) * EE + f] = a0;
  if (n0 + 1 < NN) Wh[((long)(h * NN + n0 + 1)) * EE + f] = a1;
  if (n0 + 2 < NN) Wh[((long)(h * NN + n0 + 2)) * EE + f] = a2;
  if (n0 + 3 < NN) Wh[((long)(h * NN + n0 + 3)) * EE + f] = a3;
  float asv = a_src[h * EE + f];
  float adv = a_dst[h * EE + f];
  red[0][f] = a0 * asv; red[1][f] = a0 * adv;
  red[2][f] = a1 * asv; red[3][f] = a1 * adv;
  red[4][f] = a2 * asv; red[5][f] = a2 * adv;
  red[6][f] = a3 * asv; red[7][f] = a3 * adv;
  __syncthreads();
  for (int s = 64; s > 0; s >>= 1) {
    if (f < s) {
#pragma unroll
      for (int k = 0; k < 8; k++) red[k][f] += red[k][f + s];
    }
    __syncthreads();
  }
  if (f < 4) {
    int n = n0 + f;
    if (n < NN) {
      float v1 = red[2 * f][0];
      float v2 = red[2 * f + 1][0];
      f1[h * NN + n] = v1;
      f2[h * NN + n] = v2;
      if (n < LL) {
        ef1hi[h * LL + n] = expf(v1);
        ef1lo[h * LL + n] = expf(AL * v1);
      }
    }
  }
}

// ---- K2: counting rank + pstar + w2 + counter-zero ------------------------
__global__ void k_rankw2(const float* __restrict__ f2, const float* __restrict__ f1,
                         const float* __restrict__ W_dec, const float* __restrict__ a_vec,
                         int* __restrict__ jsort, float* __restrict__ elo,
                         float* __restrict__ ehi, int* __restrict__ pstar,
                         float* __restrict__ w2, int* __restrict__ cnt) {
  int gx = blockIdx.x;
  int t = threadIdx.x;   // 128
  if (gx >= 32) {
    int idx = gx - 32;          // 0..15
    if (idx == 0 && t < 80) cnt[t] = 0;   // zero scan(64)+acc(16) counters
    int h = idx >> 2;
    int k = (idx & 3) * 128 + t;
    const float4* wp = (const float4*)&W_dec[(long)(h * HE + k) * DD];
    const float4* ap = (const float4*)&a_vec[h * DD];
    float s = 0.0f;
    for (int d = 0; d < DD / 4; d++) {
      float4 wv = wp[d];
      float4 av = ap[d];
      s += wv.x * av.x + wv.y * av.y + wv.z * av.z + wv.w * av.w;
    }
    w2[h * HE + k] = s;
    return;
  }
  __shared__ float key[LL];
  int h = gx & 3;
  int blk = gx >> 2;  // 0..7
  for (int q = t; q < LL; q += 128) key[q] = f2[h * NN + q];
  __syncthreads();
  int j0 = blk * 128 + t;
  float kv = key[j0];
  float tg = -f1[h * NN + j0];
  int rank = 0, cnt2 = 0;
  for (int q = 0; q < LL; q += 4) {
    float4 k4 = *(const float4*)&key[q];
    rank += ((k4.x < kv) || (k4.x == kv && (q + 0) < j0)) ? 1 : 0;
    rank += ((k4.y < kv) || (k4.y == kv && (q + 1) < j0)) ? 1 : 0;
    rank += ((k4.z < kv) || (k4.z == kv && (q + 2) < j0)) ? 1 : 0;
    rank += ((k4.w < kv) || (k4.w == kv && (q + 3) < j0)) ? 1 : 0;
    cnt2 += (k4.x < tg) ? 1 : 0;
    cnt2 += (k4.y < tg) ? 1 : 0;
    cnt2 += (k4.z < tg) ? 1 : 0;
    cnt2 += (k4.w < tg) ? 1 : 0;
  }
  jsort[h * LL + rank] = j0;
  elo[h * LL + rank] = expf(AL * kv);
  ehi[h * LL + rank] = expf(kv);
  pstar[h * LL + j0] = cnt2;
}

// ---- K3: chunk totals; last-arriving block per (b,h) performs the scan ----
__global__ void k_scanAB(const int* __restrict__ data, const int* __restrict__ jsort,
                         const float* __restrict__ elo, const float* __restrict__ ehi,
                         const float* __restrict__ Wh,
                         float* __restrict__ TotLo, float* __restrict__ TotHi,
                         float* __restrict__ TotLoS, float* __restrict__ TotHiS,
                         float* __restrict__ SnapLo, float* __restrict__ SnapHi,
                         float* __restrict__ SnapLoS, float* __restrict__ SnapHiS,
                         int* __restrict__ cntS) {
  int c = blockIdx.x;
  int h = blockIdx.y;
  int b = blockIdx.z;
  int t = threadIdx.x;   // 128 (1 feature/thread)
  int bh = b * HH + h;
  int q0 = c * SS;
  // vector prefetch of the chunk's metadata
  int4 ja = *(const int4*)&jsort[h * LL + q0];
  int4 jb = *(const int4*)&jsort[h * LL + q0 + 4];
  float4 ea = *(const float4*)&elo[h * LL + q0];
  float4 eb = *(const float4*)&elo[h * LL + q0 + 4];
  float4 ha = *(const float4*)&ehi[h * LL + q0];
  float4 hb = *(const float4*)&ehi[h * LL + q0 + 4];
  int jarr[8] = {ja.x, ja.y, ja.z, ja.w, jb.x, jb.y, jb.z, jb.w};
  float wla[8] = {ea.x, ea.y, ea.z, ea.w, eb.x, eb.y, eb.z, eb.w};
  float wha[8] = {ha.x, ha.y, ha.z, ha.w, hb.x, hb.y, hb.z, hb.w};
  float al = 0.0f, ah = 0.0f, sl = 0.0f, sh = 0.0f;
#pragma unroll
  for (int r = 0; r < SS; r++) {
    if (data[b * LL + jarr[r]] != 0) {
      float v = Wh[((long)(h * NN + jarr[r])) * EE + t];
      al += wla[r] * v; ah += wha[r] * v;
      sl += wla[r]; sh += wha[r];
    }
  }
  long o = (long)(bh * C1 + c);
  TotLo[o * EE + t] = al;
  TotHi[o * EE + t] = ah;
  if (t == 0) { TotLoS[o] = sl; TotHiS[o] = sh; }
  // last-block-done: the 128th block for this bh performs the exclusive scan
  __threadfence();
  __syncthreads();
  __shared__ int oldv;
  if (t == 0) oldv = atomicAdd(&cntS[bh], 1);
  __syncthreads();
  if (oldv != CC - 1) return;
  __threadfence();
  __shared__ float slv[CC];
  __shared__ float shv[CC];
  slv[t] = TotLoS[(long)bh * C1 + t];
  shv[t] = TotHiS[(long)bh * C1 + t];
  float rl = 0.0f, rh = 0.0f;
#pragma unroll 8
  for (int c2 = 0; c2 < CC; c2++) {
    long o2 = (long)(bh * C1 + c2);
    float tl = TotLo[o2 * EE + t];
    float th = TotHi[o2 * EE + t];
    SnapLo[o2 * EE + t] = rl;
    SnapHi[o2 * EE + t] = rh;
    rl += tl; rh += th;
  }
  long oc = (long)(bh * C1 + CC);
  SnapLo[oc * EE + t] = rl;
  SnapHi[oc * EE + t] = rh;
  __syncthreads();
  // scalar exclusive prefix (each thread sums slv[0..t-1] from LDS)
  float ps = 0.0f, ph = 0.0f;
  for (int q = 0; q < t; q++) { ps += slv[q]; ph += shv[q]; }
  SnapLoS[(long)bh * C1 + t] = ps;
  SnapHiS[(long)bh * C1 + t] = ph;
  if (t == 0) {
    float ts = 0.0f, th2 = 0.0f;
    for (int q = 0; q < CC; q++) { ts += slv[q]; th2 += shv[q]; }
    SnapLoS[oc] = ts;
    SnapHiS[oc] = th2;
  }
}

// ---- K6: wave-per-row: prefix-attn -> LN -> elu -> e4(bf16), g2 -> wrow ---
__global__ void k_row(const int* __restrict__ data, const float* __restrict__ Wh,
                      const int* __restrict__ pstar, const int* __restrict__ jsort,
                      const float* __restrict__ elo, const float* __restrict__ ehi,
                      const float* __restrict__ ef1hi, const float* __restrict__ ef1lo,
                      const float* __restrict__ SnapLo, const float* __restrict__ SnapHi,
                      const float* __restrict__ SnapLoS, const float* __restrict__ SnapHiS,
                      const float* __restrict__ g_enc, const float* __restrict__ b_enc,
                      const float* __restrict__ w2,
                      __hip_bfloat16* __restrict__ enc4, float* __restrict__ wrow) {
  int i = blockIdx.x;
  int b = blockIdx.y;
  int t = threadIdx.x;   // 64 lanes; features 2t, 2t+1
  if (data[b * LL + i] == 0) {
    if (t < HH) wrow[(b * HH + t) * LL + i] = 0.0f;
    return;
  }
  float x0[HH];
  float x1[HH];
#pragma unroll
  for (int h = 0; h < HH; h++) {
    int p = pstar[h * LL + i];
    int c = p / SS;
    int bh = b * HH + h;
    long o = (long)(bh * C1 + c);
    float2 rl = *(const float2*)&SnapLo[o * EE + 2 * t];
    float2 rh = *(const float2*)&SnapHi[o * EE + 2 * t];
    float rls = SnapLoS[o];
    float rhs = SnapHiS[o];
    int q0 = c * SS;
    int np = p - q0;
    // vector prefetch: jsort/elo/ehi for the whole chunk (in-workspace even
    // at p==1024 where np==0 and values are unused)
    int4 ja = *(const int4*)&jsort[h * LL + q0];
    int4 jb = *(const int4*)&jsort[h * LL + q0 + 4];
    float4 ea = *(const float4*)&elo[h * LL + q0];
    float4 eb = *(const float4*)&elo[h * LL + q0 + 4];
    float4 ha = *(const float4*)&ehi[h * LL + q0];
    float4 hb = *(const float4*)&ehi[h * LL + q0 + 4];
    int jarr[8] = {ja.x, ja.y, ja.z, ja.w, jb.x, jb.y, jb.z, jb.w};
    float wla[8] = {ea.x, ea.y, ea.z, ea.w, eb.x, eb.y, eb.z, eb.w};
    float wha[8] = {ha.x, ha.y, ha.z, ha.w, hb.x, hb.y, hb.z, hb.w};
#pragma unroll
    for (int r = 0; r < 7; r++) {
      if (r < np) {
        if (data[b * LL + jarr[r]] != 0) {
          float2 v = *(const float2*)&Wh[((long)(h * NN + jarr[r])) * EE + 2 * t];
          rl.x += wla[r] * v.x; rl.y += wla[r] * v.y;
          rh.x += wha[r] * v.x; rh.y += wha[r] * v.y;
          rls += wla[r]; rhs += wha[r];
        }
      }
    }
    long ot = (long)(bh * C1 + CC);
    float2 Th = *(const float2*)&SnapHi[ot * EE + 2 * t];
    float Ths = SnapHiS[ot];
    float eh = ef1hi[h * LL + i];
    float el = ef1lo[h * LL + i];
    float den = 1.0f / (eh * (Ths - rhs) + el * rls);
    float v0 = (eh * (Th.x - rh.x) + el * rl.x) * den;
    float v1 = (eh * (Th.y - rh.y) + el * rl.y) * den;
    x0[h] = (v0 > 0.0f) ? v0 : (expf(v0) - 1.0f);
    x1[h] = (v1 > 0.0f) ? v1 : (expf(v1) - 1.0f);
  }
  float loc = 0.0f;
#pragma unroll
  for (int h = 0; h < HH; h++) loc += x0[h] + x1[h];
#pragma unroll
  for (int s = 1; s < 64; s <<= 1) loc += __shfl_xor(loc, s, 64);
  float mu = loc * (1.0f / 512.0f);
  float q2 = 0.0f;
#pragma unroll
  for (int h = 0; h < HH; h++) {
    float d0 = x0[h] - mu;
    float d1 = x1[h] - mu;
    q2 += d0 * d0 + d1 * d1;
  }
#pragma unroll
  for (int s = 1; s < 64; s <<= 1) q2 += __shfl_xor(q2, s, 64);
  float inv = 1.0f / (sqrtf(q2 * (1.0f / 511.0f)) + EPSV);
  float e40[HH];
  float e41[HH];
  long rowo = ((long)(b * LL + i)) * HE;
#pragma unroll
  for (int h = 0; h < HH; h++) {
    float2 g = *(const float2*)&g_enc[h * EE + 2 * t];
    float2 bb = *(const float2*)&b_enc[h * EE + 2 * t];
    float v0 = g.x * (x0[h] - mu) * inv + bb.x;
    float v1 = g.y * (x1[h] - mu) * inv + bb.y;
    e40[h] = (v0 > 0.0f) ? v0 : (expf(v0) - 1.0f);
    e41[h] = (v1 > 0.0f) ? v1 : (expf(v1) - 1.0f);
    __hip_bfloat162 pk;
    pk.x = __float2bfloat16(e40[h]);
    pk.y = __float2bfloat16(e41[h]);
    *(__hip_bfloat162*)&enc4[rowo + h * EE + 2 * t] = pk;
  }
  float p0 = 0.0f, p1 = 0.0f, p2 = 0.0f, p3 = 0.0f;
#pragma unroll
  for (int h = 0; h < HH; h++) {
    float2 wA = *(const float2*)&w2[0 * HE + h * EE + 2 * t];
    float2 wB = *(const float2*)&w2[1 * HE + h * EE + 2 * t];
    float2 wC = *(const float2*)&w2[2 * HE + h * EE + 2 * t];
    float2 wD = *(const float2*)&w2[3 * HE + h * EE + 2 * t];
    p0 += e40[h] * wA.x + e41[h] * wA.y;
    p1 += e40[h] * wB.x + e41[h] * wB.y;
    p2 += e40[h] * wC.x + e41[h] * wC.y;
    p3 += e40[h] * wD.x + e41[h] * wD.y;
  }
#pragma unroll
  for (int s = 1; s < 64; s <<= 1) {
    p0 += __shfl_xor(p0, s, 64);
    p1 += __shfl_xor(p1, s, 64);
    p2 += __shfl_xor(p2, s, 64);
    p3 += __shfl_xor(p3, s, 64);
  }
  if (t < HH) {
    float g = (t == 0) ? p0 : (t == 1) ? p1 : (t == 2) ? p2 : p3;
    if (g < 0.0f) g *= AL;
    wrow[(b * HH + t) * LL + i] = expf(g);
  }
}

// ---- K7: acc partials; last-arriving block per b runs the finisher --------
__global__ __launch_bounds__(256) void k_accfin(
    const int* __restrict__ data, const __hip_bfloat16* __restrict__ enc4,
    const float* __restrict__ wrow, float* __restrict__ Upart,
    const float* __restrict__ W_dec,
    const float* __restrict__ g_dec, const float* __restrict__ b_dec,
    const float* __restrict__ V_w, const float* __restrict__ V_b,
    const float* __restrict__ o1_w, const float* __restrict__ o1_b,
    const float* __restrict__ o2_w, const float* __restrict__ o2_b,
    int* __restrict__ cntA, float* __restrict__ out) {
  int c = blockIdx.x;    // 0..31 chunks of 32 rows
  int b = blockIdx.y;
  int t = threadIdx.x;   // 256; features 2t, 2t+1 of HE
  float a00 = 0.0f, a01 = 0.0f, a10 = 0.0f, a11 = 0.0f;
  float a20 = 0.0f, a21 = 0.0f, a30 = 0.0f, a31 = 0.0f;
#pragma unroll 4
  for (int r = 0; r < 32; r++) {
    int i = c * 32 + r;
    if (data[b * LL + i] == 0) continue;
    float w0 = wrow[(b * HH + 0) * LL + i];
    float w1 = wrow[(b * HH + 1) * LL + i];
    float w2v = wrow[(b * HH + 2) * LL + i];
    float w3 = wrow[(b * HH + 3) * LL + i];
    __hip_bfloat162 pk = *(const __hip_bfloat162*)&enc4[((long)(b * LL + i)) * HE + 2 * t];
    float e0 = __bfloat162float(pk.x);
    float e1 = __bfloat162float(pk.y);
    a00 += w0 * e0; a01 += w0 * e1;
    a10 += w1 * e0; a11 += w1 * e1;
    a20 += w2v * e0; a21 += w2v * e1;
    a30 += w3 * e0; a31 += w3 * e1;
  }
  long base = (long)(b * 32 + c) * (HH * HE);
  float2 s2;
  s2.x = a00; s2.y = a01; *(float2*)&Upart[base + 0 * HE + 2 * t] = s2;
  s2.x = a10; s2.y = a11; *(float2*)&Upart[base + 1 * HE + 2 * t] = s2;
  s2.x = a20; s2.y = a21; *(float2*)&Upart[base + 2 * HE + 2 * t] = s2;
  s2.x = a30; s2.y = a31; *(float2*)&Upart[base + 3 * HE + 2 * t] = s2;
  // last-block-done: 32nd block for this b runs the finisher
  __threadfence();
  __syncthreads();
  __shared__ int oldv;
  if (t == 0) oldv = atomicAdd(&cntA[b], 1);
  __syncthreads();
  if (oldv != 31) return;
  __threadfence();
  __shared__ float zs[4];
  __shared__ float Ut[HH * HE];
  __shared__ float red2[2][DD];
  __shared__ float red[DD];
  __shared__ float xs[DD];
  // z[hp]
  int rg = t >> 6;
  int lane = t & 63;
  float zp = 0.0f;
#pragma unroll
  for (int k = 0; k < 16; k++) zp += wrow[(b * HH + rg) * LL + lane + 64 * k];
#pragma unroll
  for (int d = 1; d < 64; d <<= 1) zp += __shfl_xor(zp, d, 64);
  if (lane == 0) zs[rg] = 0.25f / (1.0f + zp);
  // U sums: 8 k's per thread over 32 chunks
  float us0 = 0.0f, us1 = 0.0f, us2 = 0.0f, us3 = 0.0f;
  float us4 = 0.0f, us5 = 0.0f, us6 = 0.0f, us7 = 0.0f;
  for (int cc = 0; cc < 32; cc++) {
    const float* p = &Upart[(long)(b * 32 + cc) * (HH * HE)];
    us0 += p[t];        us1 += p[t + 256];
    us2 += p[t + 512];  us3 += p[t + 768];
    us4 += p[t + 1024]; us5 += p[t + 1280];
    us6 += p[t + 1536]; us7 += p[t + 1792];
  }
  __syncthreads();
  Ut[t]        = us0 * zs[0]; Ut[t + 256]  = us1 * zs[(t + 256) >> 9];
  Ut[t + 512]  = us2 * zs[1]; Ut[t + 768]  = us3 * zs[(t + 768) >> 9];
  Ut[t + 1024] = us4 * zs[2]; Ut[t + 1280] = us5 * zs[(t + 1280) >> 9];
  Ut[t + 1536] = us6 * zs[3]; Ut[t + 1792] = us7 * zs[(t + 1792) >> 9];
  __syncthreads();
  // dec[f] = sum_k Ut[k] * W_dec[k*DD+f]
  int f = t & 127;
  int kg = t >> 7;   // 0..1
  {
    float s = 0.0f;
    int k0 = kg * 1024;
#pragma unroll 8
    for (int kk = k0; kk < k0 + 1024; kk++) {
      s += Ut[kk] * W_dec[(long)kk * DD + f];
    }
    red2[kg][f] = s;
  }
  __syncthreads();
  float dec = 0.0f;
  if (t < DD) {
    dec = red2[0][t] + red2[1][t];
    red[t] = dec;
  }
  __syncthreads();
  for (int s = 64; s > 0; s >>= 1) {
    if (t < s) red[t] += red[t + s];
    __syncthreads();
  }
  float mu = red[0] / 128.0f;
  __syncthreads();
  float dd = 0.0f;
  if (t < DD) { dd = dec - mu; red[t] = dd * dd; }
  __syncthreads();
  for (int s = 64; s > 0; s >>= 1) {
    if (t < s) red[t] += red[t + s];
    __syncthreads();
  }
  float sd = sqrtf(red[0] / 127.0f);
  __syncthreads();
  if (t < DD) {
    float v = g_dec[t] * dd / (sd + EPSV) + b_dec[t];
    if (v < 0.0f) v = 0.0f;
    xs[t] = v;
  }
  __syncthreads();
  {
    float s = 0.0f;
    int k0 = kg * 64;
#pragma unroll
    for (int k = k0; k < k0 + 64; k++) s += xs[k] * V_w[k * DD + f];
    red2[kg][f] = s;
  }
  __syncthreads();
  float xv = 0.0f;
  if (t < DD) {
    xv = red2[0][t] + red2[1][t] + V_b[t];
  }
  __syncthreads();
  if (t < DD) xs[t] = xv;
  __syncthreads();
  {
    float s = 0.0f;
    int k0 = kg * 64;
#pragma unroll
    for (int k = k0; k < k0 + 64; k++) s += xs[k] * o1_w[k * DD + f];
    red2[kg][f] = s;
  }
  __syncthreads();
  if (t < DD) {
    float hv = red2[0][t] + red2[1][t] + o1_b[t];
    if (hv < 0.0f) hv = 0.0f;
    red[t] = hv * o2_w[t];
  }
  __syncthreads();
  for (int s = 64; s > 0; s >>= 1) {
    if (t < s) red[t] += red[t + s];
    __syncthreads();
  }
  if (t == 0) out[b] = red[0] + o2_b[0];
}

extern "C" void kernel_launch(void* const* d_in, const int* in_sizes, int n_in,
                              void* d_out, int out_size, void* d_ws, size_t ws_size,
                              hipStream_t stream) {
  const int* data    = (const int*)d_in[0];
  const float* embed  = (const float*)d_in[1];
  const float* W_enc  = (const float*)d_in[2];
  const float* a_esrc = (const float*)d_in[3];
  const float* a_edst = (const float*)d_in[4];
  const float* g_enc  = (const float*)d_in[5];
  const float* b_enc  = (const float*)d_in[6];
  const float* W_dec  = (const float*)d_in[7];
  const float* a_ddst = (const float*)d_in[9];
  const float* g_dec  = (const float*)d_in[10];
  const float* b_dec  = (const float*)d_in[11];
  const float* V_w    = (const float*)d_in[12];
  const float* V_b    = (const float*)d_in[13];
  const float* o1_w   = (const float*)d_in[14];
  const float* o1_b   = (const float*)d_in[15];
  const float* o2_w   = (const float*)d_in[16];
  const float* o2_b   = (const float*)d_in[17];
  float* out = (float*)d_out;               // fp32 output

  float* w = (float*)d_ws;
  float* Wh    = w + O_WH;
  float* f1    = w + O_F1;
  float* f2    = w + O_F2;
  float* elo   = w + O_ELO;
  float* ehi   = w + O_EHI;
  float* ef1hi = w + O_EF1H;
  float* ef1lo = w + O_EF1L;
  float* w2    = w + O_W2;
  float* SnapLo  = w + O_SLO;
  float* SnapHi  = w + O_SHI;
  float* SnapLoS = w + O_SLOS;
  float* SnapHiS = w + O_SHIS;
  float* TotLo   = w + O_TLO;
  float* TotHi   = w + O_THI;
  float* TotLoS  = w + O_TLOS;
  float* TotHiS  = w + O_THIS;
  float* wrow  = w + O_WR;
  float* Upart = w + O_UP;
  int* jsort   = (int*)(w + O_JS);
  int* pstar   = (int*)(w + O_PS);
  __hip_bfloat16* enc4 = (__hip_bfloat16*)(w + O_E4);
  int* cnt     = (int*)(w + O_CNT);

  VGNN_27049704030896_kernel<<<dim3((NN + 3) / 4, HH), 128, 0, stream>>>(
      embed, W_enc, a_esrc, a_edst, Wh, f1, f2, ef1hi, ef1lo);
  k_rankw2<<<48, 128, 0, stream>>>(f2, f1, W_dec, a_ddst,
                                   jsort, elo, ehi, pstar, w2, cnt);
  k_scanAB<<<dim3(CC, HH, BB), 128, 0, stream>>>(data, jsort, elo, ehi, Wh,
                                                 TotLo, TotHi, TotLoS, TotHiS,
                                                 SnapLo, SnapHi, SnapLoS, SnapHiS,
                                                 cnt);
  k_row <<<dim3(LL, BB), 64, 0, stream>>>(data, Wh, pstar, jsort, elo, ehi,
                                          ef1hi, ef1lo, SnapLo, SnapHi,
                                          SnapLoS, SnapHiS, g_enc, b_enc, w2,
                                          enc4, wrow);
  k_accfin<<<dim3(32, BB), 256, 0, stream>>>(data, enc4, wrow, Upart, W_dec,
                                             g_dec, b_dec, V_w, V_b,
                                             o1_w, o1_b, o2_w, o2_b,
                                             cnt + 64, out);
}

// Round 5
// 218.640 us; speedup vs baseline: 3.1264x; 3.1264x over previous
//
#include <hip/hip_runtime.h>
#include <hip/hip_bf16.h>

#define BB 16
#define LL 1024
#define EE 128
#define HH 4
#define DD 128
#define NN 1025
#define HE 512
#define AL 0.2f
#define EPSV 1e-6f
#define SS 8
#define CC 128
#define C1 129

// workspace float offsets (footprint unchanged; Tot* alias enc4 region — dead
// before k_row writes enc4). Upart: 32 chunks x 16 b x 2048 = exactly fills to O_JS.
#define O_WH   0
#define O_F1   524800
#define O_F2   528900
#define O_ELO  537096
#define O_EHI  541192
#define O_EF1H 545288
#define O_EF1L 549384
#define O_W2   553480
#define O_SLO  555528
#define O_SHI  1612296
#define O_SLOS 2669064
#define O_SHIS 2677320
#define O_WR   2685576
#define O_UP   2751112
#define O_JS   3799688
#define O_PS   3803784
#define O_E4   3807880
#define O_TLO  3807880
#define O_THI  4864648
#define O_TLOS 5921416
#define O_THIS 5929672

// ---- K1: Wh + f1/f2 + exp tables; 4 rows/block for W_enc L2 reuse ---------
__global__ void VGNN_27049704030896_kernel(const float* __restrict__ embed,
                                           const float* __restrict__ W_enc,
                                           const float* __restrict__ a_src,
                                           const float* __restrict__ a_dst,
                                           float* __restrict__ Wh,
                                           float* __restrict__ f1,
                                           float* __restrict__ f2,
                                           float* __restrict__ ef1hi,
                                           float* __restrict__ ef1lo) {
  __shared__ float red[8][EE];
  int n0 = blockIdx.x * 4;
  int h = blockIdx.y;
  int f = threadIdx.x;   // 128
  const float* ep0 = embed + (long)((n0 + 0 < NN) ? n0 + 0 : NN - 1) * EE;
  const float* ep1 = embed + (long)((n0 + 1 < NN) ? n0 + 1 : NN - 1) * EE;
  const float* ep2 = embed + (long)((n0 + 2 < NN) ? n0 + 2 : NN - 1) * EE;
  const float* ep3 = embed + (long)((n0 + 3 < NN) ? n0 + 3 : NN - 1) * EE;
  float m0 = (n0 + 0 > 0 && n0 + 0 < NN) ? 1.0f : 0.0f;
  float m1 = (n0 + 1 > 0 && n0 + 1 < NN) ? 1.0f : 0.0f;
  float m2 = (n0 + 2 > 0 && n0 + 2 < NN) ? 1.0f : 0.0f;
  float m3 = (n0 + 3 > 0 && n0 + 3 < NN) ? 1.0f : 0.0f;
  float a0 = 0.0f, a1 = 0.0f, a2 = 0.0f, a3 = 0.0f;
  for (int e = 0; e < EE; e++) {
    float wv = W_enc[((long)(h * EE + e)) * EE + f];
    a0 += ep0[e] * wv; a1 += ep1[e] * wv;
    a2 += ep2[e] * wv; a3 += ep3[e] * wv;
  }
  a0 *= m0; a1 *= m1; a2 *= m2; a3 *= m3;
  if (n0 + 0 < NN) Wh[((long)(h * NN + n0 + 0)) * EE + f] = a0;
  if (n0 + 1 < NN) Wh[((long)(h * NN + n0 + 1)) * EE + f] = a1;
  if (n0 + 2 < NN) Wh[((long)(h * NN + n0 + 2)) * EE + f] = a2;
  if (n0 + 3 < NN) Wh[((long)(h * NN + n0 + 3)) * EE + f] = a3;
  float asv = a_src[h * EE + f];
  float adv = a_dst[h * EE + f];
  red[0][f] = a0 * asv; red[1][f] = a0 * adv;
  red[2][f] = a1 * asv; red[3][f] = a1 * adv;
  red[4][f] = a2 * asv; red[5][f] = a2 * adv;
  red[6][f] = a3 * asv; red[7][f] = a3 * adv;
  __syncthreads();
  for (int s = 64; s > 0; s >>= 1) {
    if (f < s) {
#pragma unroll
      for (int k = 0; k < 8; k++) red[k][f] += red[k][f + s];
    }
    __syncthreads();
  }
  if (f < 4) {
    int n = n0 + f;
    if (n < NN) {
      float v1 = red[2 * f][0];
      float v2 = red[2 * f + 1][0];
      f1[h * NN + n] = v1;
      f2[h * NN + n] = v2;
      if (n < LL) {
        ef1hi[h * LL + n] = expf(v1);
        ef1lo[h * LL + n] = expf(AL * v1);
      }
    }
  }
}

// ---- K2: counting rank + pstar, with k_w2 fused in (blocks 32..47) --------
__global__ void k_rankw2(const float* __restrict__ f2, const float* __restrict__ f1,
                         const float* __restrict__ W_dec, const float* __restrict__ a_vec,
                         int* __restrict__ jsort, float* __restrict__ elo,
                         float* __restrict__ ehi, int* __restrict__ pstar,
                         float* __restrict__ w2) {
  int gx = blockIdx.x;
  int t = threadIdx.x;   // 128
  if (gx >= 32) {
    int idx = gx - 32;          // 0..15
    int h = idx >> 2;
    int k = (idx & 3) * 128 + t;
    const float4* wp = (const float4*)&W_dec[(long)(h * HE + k) * DD];
    const float4* ap = (const float4*)&a_vec[h * DD];
    float s = 0.0f;
    for (int d = 0; d < DD / 4; d++) {
      float4 wv = wp[d];
      float4 av = ap[d];
      s += wv.x * av.x + wv.y * av.y + wv.z * av.z + wv.w * av.w;
    }
    w2[h * HE + k] = s;
    return;
  }
  __shared__ float key[LL];
  int h = gx & 3;
  int blk = gx >> 2;  // 0..7
  for (int q = t; q < LL; q += 128) key[q] = f2[h * NN + q];
  __syncthreads();
  int j0 = blk * 128 + t;
  float kv = key[j0];
  float tg = -f1[h * NN + j0];
  int rank = 0, cnt2 = 0;
  for (int q = 0; q < LL; q += 4) {
    float4 k4 = *(const float4*)&key[q];
    rank += ((k4.x < kv) || (k4.x == kv && (q + 0) < j0)) ? 1 : 0;
    rank += ((k4.y < kv) || (k4.y == kv && (q + 1) < j0)) ? 1 : 0;
    rank += ((k4.z < kv) || (k4.z == kv && (q + 2) < j0)) ? 1 : 0;
    rank += ((k4.w < kv) || (k4.w == kv && (q + 3) < j0)) ? 1 : 0;
    cnt2 += (k4.x < tg) ? 1 : 0;
    cnt2 += (k4.y < tg) ? 1 : 0;
    cnt2 += (k4.z < tg) ? 1 : 0;
    cnt2 += (k4.w < tg) ? 1 : 0;
  }
  jsort[h * LL + rank] = j0;
  elo[h * LL + rank] = expf(AL * kv);
  ehi[h * LL + rank] = expf(kv);
  pstar[h * LL + j0] = cnt2;
}

// ---- K3: per-chunk masked weighted totals (vector metadata prefetch) ------
__global__ void k_scanA(const int* __restrict__ data, const int* __restrict__ jsort,
                        const float* __restrict__ elo, const float* __restrict__ ehi,
                        const float* __restrict__ Wh,
                        float* __restrict__ TotLo, float* __restrict__ TotHi,
                        float* __restrict__ TotLoS, float* __restrict__ TotHiS) {
  int c = blockIdx.x;
  int h = blockIdx.y;
  int b = blockIdx.z;
  int t = threadIdx.x;   // 128 (1 feature/thread)
  int bh = b * HH + h;
  int q0 = c * SS;
  int4 ja = *(const int4*)&jsort[h * LL + q0];
  int4 jb = *(const int4*)&jsort[h * LL + q0 + 4];
  float4 ea = *(const float4*)&elo[h * LL + q0];
  float4 eb = *(const float4*)&elo[h * LL + q0 + 4];
  float4 ha = *(const float4*)&ehi[h * LL + q0];
  float4 hb = *(const float4*)&ehi[h * LL + q0 + 4];
  int jarr[8] = {ja.x, ja.y, ja.z, ja.w, jb.x, jb.y, jb.z, jb.w};
  float wla[8] = {ea.x, ea.y, ea.z, ea.w, eb.x, eb.y, eb.z, eb.w};
  float wha[8] = {ha.x, ha.y, ha.z, ha.w, hb.x, hb.y, hb.z, hb.w};
  float al = 0.0f, ah = 0.0f, sl = 0.0f, sh = 0.0f;
#pragma unroll
  for (int r = 0; r < SS; r++) {
    if (data[b * LL + jarr[r]] != 0) {
      float v = Wh[((long)(h * NN + jarr[r])) * EE + t];
      al += wla[r] * v; ah += wha[r] * v;
      sl += wla[r]; sh += wha[r];
    }
  }
  long o = (long)(bh * C1 + c);
  TotLo[o * EE + t] = al;
  TotHi[o * EE + t] = ah;
  if (t == 0) { TotLoS[o] = sl; TotHiS[o] = sh; }
}

// ---- K4: exclusive scan, separate in/out arrays so loads pipeline ---------
__global__ void k_scanB(const float* __restrict__ TotLo, const float* __restrict__ TotHi,
                        const float* __restrict__ TotLoS, const float* __restrict__ TotHiS,
                        float* __restrict__ SnapLo, float* __restrict__ SnapHi,
                        float* __restrict__ SnapLoS, float* __restrict__ SnapHiS) {
  int bh = blockIdx.x;
  int f = threadIdx.x & 127;
  int a = threadIdx.x >> 7;   // 0: Lo-half, 1: Hi-half (wave-uniform)
  const float* __restrict__ T  = a ? TotHi  : TotLo;
  const float* __restrict__ Ts = a ? TotHiS : TotLoS;
  float* __restrict__ S  = a ? SnapHi  : SnapLo;
  float* __restrict__ Ss = a ? SnapHiS : SnapLoS;
  float r = 0.0f, rs = 0.0f;
#pragma unroll 8
  for (int c = 0; c < CC; c++) {
    long o = (long)(bh * C1 + c);
    float tv = T[o * EE + f];
    float ts = Ts[o];
    S[o * EE + f] = r;
    if (f == 0) Ss[o] = rs;
    r += tv; rs += ts;
  }
  long o = (long)(bh * C1 + CC);
  S[o * EE + f] = r;
  if (f == 0) Ss[o] = rs;
}

// ---- K6: wave-per-row: prefix-attn -> LN -> elu -> e4(bf16), g2 -> wrow ---
__global__ void k_row(const int* __restrict__ data, const float* __restrict__ Wh,
                      const int* __restrict__ pstar, const int* __restrict__ jsort,
                      const float* __restrict__ elo, const float* __restrict__ ehi,
                      const float* __restrict__ ef1hi, const float* __restrict__ ef1lo,
                      const float* __restrict__ SnapLo, const float* __restrict__ SnapHi,
                      const float* __restrict__ SnapLoS, const float* __restrict__ SnapHiS,
                      const float* __restrict__ g_enc, const float* __restrict__ b_enc,
                      const float* __restrict__ w2,
                      __hip_bfloat16* __restrict__ enc4, float* __restrict__ wrow) {
  int i = blockIdx.x;
  int b = blockIdx.y;
  int t = threadIdx.x;   // 64 lanes; features 2t, 2t+1
  if (data[b * LL + i] == 0) {
    if (t < HH) wrow[(b * HH + t) * LL + i] = 0.0f;
    return;
  }
  float x0[HH];
  float x1[HH];
#pragma unroll
  for (int h = 0; h < HH; h++) {
    int p = pstar[h * LL + i];
    int c = p / SS;
    int bh = b * HH + h;
    long o = (long)(bh * C1 + c);
    float2 rl = *(const float2*)&SnapLo[o * EE + 2 * t];
    float2 rh = *(const float2*)&SnapHi[o * EE + 2 * t];
    float rls = SnapLoS[o];
    float rhs = SnapHiS[o];
    int q0 = c * SS;
    int np = p - q0;
    // vector prefetch: jsort/elo/ehi for the whole chunk (in-workspace even
    // at p==1024 where np==0 and values are unused)
    int4 ja = *(const int4*)&jsort[h * LL + q0];
    int4 jb = *(const int4*)&jsort[h * LL + q0 + 4];
    float4 ea = *(const float4*)&elo[h * LL + q0];
    float4 eb = *(const float4*)&elo[h * LL + q0 + 4];
    float4 ha = *(const float4*)&ehi[h * LL + q0];
    float4 hb = *(const float4*)&ehi[h * LL + q0 + 4];
    int jarr[8] = {ja.x, ja.y, ja.z, ja.w, jb.x, jb.y, jb.z, jb.w};
    float wla[8] = {ea.x, ea.y, ea.z, ea.w, eb.x, eb.y, eb.z, eb.w};
    float wha[8] = {ha.x, ha.y, ha.z, ha.w, hb.x, hb.y, hb.z, hb.w};
#pragma unroll
    for (int r = 0; r < 7; r++) {
      if (r < np) {
        if (data[b * LL + jarr[r]] != 0) {
          float2 v = *(const float2*)&Wh[((long)(h * NN + jarr[r])) * EE + 2 * t];
          rl.x += wla[r] * v.x; rl.y += wla[r] * v.y;
          rh.x += wha[r] * v.x; rh.y += wha[r] * v.y;
          rls += wla[r]; rhs += wha[r];
        }
      }
    }
    long ot = (long)(bh * C1 + CC);
    float2 Th = *(const float2*)&SnapHi[ot * EE + 2 * t];
    float Ths = SnapHiS[ot];
    float eh = ef1hi[h * LL + i];
    float el = ef1lo[h * LL + i];
    float den = 1.0f / (eh * (Ths - rhs) + el * rls);
    float v0 = (eh * (Th.x - rh.x) + el * rl.x) * den;
    float v1 = (eh * (Th.y - rh.y) + el * rl.y) * den;
    x0[h] = (v0 > 0.0f) ? v0 : (expf(v0) - 1.0f);
    x1[h] = (v1 > 0.0f) ? v1 : (expf(v1) - 1.0f);
  }
  float loc = 0.0f;
#pragma unroll
  for (int h = 0; h < HH; h++) loc += x0[h] + x1[h];
#pragma unroll
  for (int s = 1; s < 64; s <<= 1) loc += __shfl_xor(loc, s, 64);
  float mu = loc * (1.0f / 512.0f);
  float q2 = 0.0f;
#pragma unroll
  for (int h = 0; h < HH; h++) {
    float d0 = x0[h] - mu;
    float d1 = x1[h] - mu;
    q2 += d0 * d0 + d1 * d1;
  }
#pragma unroll
  for (int s = 1; s < 64; s <<= 1) q2 += __shfl_xor(q2, s, 64);
  float inv = 1.0f / (sqrtf(q2 * (1.0f / 511.0f)) + EPSV);
  float e40[HH];
  float e41[HH];
  long rowo = ((long)(b * LL + i)) * HE;
#pragma unroll
  for (int h = 0; h < HH; h++) {
    float2 g = *(const float2*)&g_enc[h * EE + 2 * t];
    float2 bb = *(const float2*)&b_enc[h * EE + 2 * t];
    float v0 = g.x * (x0[h] - mu) * inv + bb.x;
    float v1 = g.y * (x1[h] - mu) * inv + bb.y;
    e40[h] = (v0 > 0.0f) ? v0 : (expf(v0) - 1.0f);
    e41[h] = (v1 > 0.0f) ? v1 : (expf(v1) - 1.0f);
    __hip_bfloat162 pk;
    pk.x = __float2bfloat16(e40[h]);
    pk.y = __float2bfloat16(e41[h]);
    *(__hip_bfloat162*)&enc4[rowo + h * EE + 2 * t] = pk;
  }
  float p0 = 0.0f, p1 = 0.0f, p2 = 0.0f, p3 = 0.0f;
#pragma unroll
  for (int h = 0; h < HH; h++) {
    float2 wA = *(const float2*)&w2[0 * HE + h * EE + 2 * t];
    float2 wB = *(const float2*)&w2[1 * HE + h * EE + 2 * t];
    float2 wC = *(const float2*)&w2[2 * HE + h * EE + 2 * t];
    float2 wD = *(const float2*)&w2[3 * HE + h * EE + 2 * t];
    p0 += e40[h] * wA.x + e41[h] * wA.y;
    p1 += e40[h] * wB.x + e41[h] * wB.y;
    p2 += e40[h] * wC.x + e41[h] * wC.y;
    p3 += e40[h] * wD.x + e41[h] * wD.y;
  }
#pragma unroll
  for (int s = 1; s < 64; s <<= 1) {
    p0 += __shfl_xor(p0, s, 64);
    p1 += __shfl_xor(p1, s, 64);
    p2 += __shfl_xor(p2, s, 64);
    p3 += __shfl_xor(p3, s, 64);
  }
  if (t < HH) {
    float g = (t == 0) ? p0 : (t == 1) ? p1 : (t == 2) ? p2 : p3;
    if (g < 0.0f) g *= AL;
    wrow[(b * HH + t) * LL + i] = expf(g);
  }
}

// ---- K7: register-accumulated weighted row sums (512 blocks) --------------
__global__ __launch_bounds__(256) void k_acc(
    const int* __restrict__ data, const __hip_bfloat16* __restrict__ enc4,
    const float* __restrict__ wrow, float* __restrict__ Upart) {
  int c = blockIdx.x;    // 0..31 chunks of 32 rows
  int b = blockIdx.y;
  int t = threadIdx.x;   // 256; features 2t, 2t+1 of HE
  float a00 = 0.0f, a01 = 0.0f, a10 = 0.0f, a11 = 0.0f;
  float a20 = 0.0f, a21 = 0.0f, a30 = 0.0f, a31 = 0.0f;
#pragma unroll 4
  for (int r = 0; r < 32; r++) {
    int i = c * 32 + r;
    if (data[b * LL + i] == 0) continue;
    float w0 = wrow[(b * HH + 0) * LL + i];
    float w1 = wrow[(b * HH + 1) * LL + i];
    float w2v = wrow[(b * HH + 2) * LL + i];
    float w3 = wrow[(b * HH + 3) * LL + i];
    __hip_bfloat162 pk = *(const __hip_bfloat162*)&enc4[((long)(b * LL + i)) * HE + 2 * t];
    float e0 = __bfloat162float(pk.x);
    float e1 = __bfloat162float(pk.y);
    a00 += w0 * e0; a01 += w0 * e1;
    a10 += w1 * e0; a11 += w1 * e1;
    a20 += w2v * e0; a21 += w2v * e1;
    a30 += w3 * e0; a31 += w3 * e1;
  }
  long base = (long)(b * 32 + c) * (HH * HE);
  float2 s2;
  s2.x = a00; s2.y = a01; *(float2*)&Upart[base + 0 * HE + 2 * t] = s2;
  s2.x = a10; s2.y = a11; *(float2*)&Upart[base + 1 * HE + 2 * t] = s2;
  s2.x = a20; s2.y = a21; *(float2*)&Upart[base + 2 * HE + 2 * t] = s2;
  s2.x = a30; s2.y = a31; *(float2*)&Upart[base + 3 * HE + 2 * t] = s2;
}

// ---- K8: fused finisher: Upart-sum + z + U*W_dec + LN + V + o1 + o2 -------
__global__ __launch_bounds__(1024) void k_fin(
    const float* __restrict__ Upart, const float* __restrict__ wrow,
    const float* __restrict__ W_dec,
    const float* __restrict__ g_dec, const float* __restrict__ b_dec,
    const float* __restrict__ V_w, const float* __restrict__ V_b,
    const float* __restrict__ o1_w, const float* __restrict__ o1_b,
    const float* __restrict__ o2_w, const float* __restrict__ o2_b,
    float* __restrict__ out) {
  __shared__ float Ut[HH * HE];     // 8 KB scaled U (incl. 0.25/(1+z))
  __shared__ float zr[4][256];      // 4 KB z partials
  __shared__ float zs[4];
  __shared__ float red8[8][DD];     // 4 KB matvec partials
  __shared__ float red[DD];
  __shared__ float xs[DD];
  int b = blockIdx.x;
  int t = threadIdx.x;     // 1024
  int rg = t >> 8;         // 0..3
  int tt = t & 255;
  // --- z partials (independent loads) ---
  float zp = wrow[(b * HH + rg) * LL + tt]
           + wrow[(b * HH + rg) * LL + tt + 256]
           + wrow[(b * HH + rg) * LL + tt + 512]
           + wrow[(b * HH + rg) * LL + tt + 768];
  zr[rg][tt] = zp;
  // --- U sums: each thread 2 k's, 32 independent loads each ---
  float us0 = 0.0f, us1 = 0.0f;
#pragma unroll 8
  for (int c = 0; c < 32; c++) {
    const float* p = &Upart[(long)(b * 32 + c) * (HH * HE)];
    us0 += p[t];
    us1 += p[t + 1024];
  }
  __syncthreads();
  int wid = t >> 6;
  int lane = t & 63;
  if (wid < 4) {
    float s = zr[wid][lane] + zr[wid][lane + 64] + zr[wid][lane + 128] + zr[wid][lane + 192];
#pragma unroll
    for (int d = 1; d < 64; d <<= 1) s += __shfl_xor(s, d, 64);
    if (lane == 0) zs[wid] = 0.25f / (1.0f + s);
  }
  __syncthreads();
  Ut[t] = us0 * zs[t >> 9];
  Ut[t + 1024] = us1 * zs[(t + 1024) >> 9];
  __syncthreads();
  // --- dec[f] = sum_k2 Ut[k2] * W_dec[k2*DD + f] ---
  int f = t & 127;
  int kg = t >> 7;   // 0..7
  {
    float s = 0.0f;
    int k0 = kg * 256;
#pragma unroll 8
    for (int kk = k0; kk < k0 + 256; kk++) {
      s += Ut[kk] * W_dec[(long)kk * DD + f];
    }
    red8[kg][f] = s;
  }
  __syncthreads();
  float dec = 0.0f;
  if (t < DD) {
#pragma unroll
    for (int g = 0; g < 8; g++) dec += red8[g][t];
    red[t] = dec;
  }
  __syncthreads();
  // --- LN -> relu -> V -> o1 -> o2 ---
  for (int s = 64; s > 0; s >>= 1) {
    if (t < s) red[t] += red[t + s];
    __syncthreads();
  }
  float mu = red[0] / 128.0f;
  __syncthreads();
  float dd = 0.0f;
  if (t < DD) { dd = dec - mu; red[t] = dd * dd; }
  __syncthreads();
  for (int s = 64; s > 0; s >>= 1) {
    if (t < s) red[t] += red[t + s];
    __syncthreads();
  }
  float sd = sqrtf(red[0] / 127.0f);
  __syncthreads();
  if (t < DD) {
    float v = g_dec[t] * dd / (sd + EPSV) + b_dec[t];
    if (v < 0.0f) v = 0.0f;
    xs[t] = v;
  }
  __syncthreads();
  {
    float s = 0.0f;
    int k0 = kg * 16;
#pragma unroll
    for (int k = k0; k < k0 + 16; k++) s += xs[k] * V_w[k * DD + f];
    red8[kg][f] = s;
  }
  __syncthreads();
  float xv = 0.0f;
  if (t < DD) {
#pragma unroll
    for (int g = 0; g < 8; g++) xv += red8[g][t];
    xv += V_b[t];
  }
  __syncthreads();
  if (t < DD) xs[t] = xv;
  __syncthreads();
  {
    float s = 0.0f;
    int k0 = kg * 16;
#pragma unroll
    for (int k = k0; k < k0 + 16; k++) s += xs[k] * o1_w[k * DD + f];
    red8[kg][f] = s;
  }
  __syncthreads();
  if (t < DD) {
    float hv = 0.0f;
#pragma unroll
    for (int g = 0; g < 8; g++) hv += red8[g][t];
    hv += o1_b[t];
    if (hv < 0.0f) hv = 0.0f;
    red[t] = hv * o2_w[t];
  }
  __syncthreads();
  for (int s = 64; s > 0; s >>= 1) {
    if (t < s) red[t] += red[t + s];
    __syncthreads();
  }
  if (t == 0) out[b] = red[0] + o2_b[0];
}

extern "C" void kernel_launch(void* const* d_in, const int* in_sizes, int n_in,
                              void* d_out, int out_size, void* d_ws, size_t ws_size,
                              hipStream_t stream) {
  const int* data    = (const int*)d_in[0];
  const float* embed  = (const float*)d_in[1];
  const float* W_enc  = (const float*)d_in[2];
  const float* a_esrc = (const float*)d_in[3];
  const float* a_edst = (const float*)d_in[4];
  const float* g_enc  = (const float*)d_in[5];
  const float* b_enc  = (const float*)d_in[6];
  const float* W_dec  = (const float*)d_in[7];
  const float* a_ddst = (const float*)d_in[9];
  const float* g_dec  = (const float*)d_in[10];
  const float* b_dec  = (const float*)d_in[11];
  const float* V_w    = (const float*)d_in[12];
  const float* V_b    = (const float*)d_in[13];
  const float* o1_w   = (const float*)d_in[14];
  const float* o1_b   = (const float*)d_in[15];
  const float* o2_w   = (const float*)d_in[16];
  const float* o2_b   = (const float*)d_in[17];
  float* out = (float*)d_out;               // fp32 output

  float* w = (float*)d_ws;
  float* Wh    = w + O_WH;
  float* f1    = w + O_F1;
  float* f2    = w + O_F2;
  float* elo   = w + O_ELO;
  float* ehi   = w + O_EHI;
  float* ef1hi = w + O_EF1H;
  float* ef1lo = w + O_EF1L;
  float* w2    = w + O_W2;
  float* SnapLo  = w + O_SLO;
  float* SnapHi  = w + O_SHI;
  float* SnapLoS = w + O_SLOS;
  float* SnapHiS = w + O_SHIS;
  float* TotLo   = w + O_TLO;
  float* TotHi   = w + O_THI;
  float* TotLoS  = w + O_TLOS;
  float* TotHiS  = w + O_THIS;
  float* wrow  = w + O_WR;
  float* Upart = w + O_UP;
  int* jsort   = (int*)(w + O_JS);
  int* pstar   = (int*)(w + O_PS);
  __hip_bfloat16* enc4 = (__hip_bfloat16*)(w + O_E4);

  VGNN_27049704030896_kernel<<<dim3((NN + 3) / 4, HH), 128, 0, stream>>>(
      embed, W_enc, a_esrc, a_edst, Wh, f1, f2, ef1hi, ef1lo);
  k_rankw2<<<48, 128, 0, stream>>>(f2, f1, W_dec, a_ddst,
                                   jsort, elo, ehi, pstar, w2);
  k_scanA<<<dim3(CC, HH, BB), 128, 0, stream>>>(data, jsort, elo, ehi, Wh,
                                                TotLo, TotHi, TotLoS, TotHiS);
  k_scanB<<<BB * HH, 256, 0, stream>>>(TotLo, TotHi, TotLoS, TotHiS,
                                       SnapLo, SnapHi, SnapLoS, SnapHiS);
  k_row <<<dim3(LL, BB), 64, 0, stream>>>(data, Wh, pstar, jsort, elo, ehi,
                                          ef1hi, ef1lo, SnapLo, SnapHi,
                                          SnapLoS, SnapHiS, g_enc, b_enc, w2,
                                          enc4, wrow);
  k_acc <<<dim3(32, BB), 256, 0, stream>>>(data, enc4, wrow, Upart);
  k_fin <<<BB, 1024, 0, stream>>>(Upart, wrow, W_dec,
                                  g_dec, b_dec, V_w, V_b,
                                  o1_w, o1_b, o2_w, o2_b, out);
}

// Round 6
// 217.093 us; speedup vs baseline: 3.1486x; 1.0071x over previous
//
#include <hip/hip_runtime.h>
#include <hip/hip_bf16.h>

#define BB 16
#define LL 1024
#define EE 128
#define HH 4
#define DD 128
#define NN 1025
#define HE 512
#define AL 0.2f
#define EPSV 1e-6f
#define SS 8
#define CC 128
#define C1 129

// workspace float offsets (footprint unchanged vs verified layout).
// Tot* arrays are GONE (scan fused, intra-block). Upart: 32 chunks x 16 b.
#define O_WH   0
#define O_F1   524800
#define O_F2   528900
#define O_ELO  537096
#define O_EHI  541192
#define O_EF1H 545288
#define O_EF1L 549384
#define O_W2   553480
#define O_SLO  555528
#define O_SHI  1612296
#define O_SLOS 2669064
#define O_SHIS 2677320
#define O_WR   2685576
#define O_UP   2751112
#define O_JS   3799688
#define O_PS   3803784
#define O_E4   3807880

// ---- K1: Wh + f1/f2 + exp tables; 4 rows/block for W_enc L2 reuse ---------
__global__ void VGNN_27049704030896_kernel(const float* __restrict__ embed,
                                           const float* __restrict__ W_enc,
                                           const float* __restrict__ a_src,
                                           const float* __restrict__ a_dst,
                                           float* __restrict__ Wh,
                                           float* __restrict__ f1,
                                           float* __restrict__ f2,
                                           float* __restrict__ ef1hi,
                                           float* __restrict__ ef1lo) {
  __shared__ float red[8][EE];
  int n0 = blockIdx.x * 4;
  int h = blockIdx.y;
  int f = threadIdx.x;   // 128
  const float* ep0 = embed + (long)((n0 + 0 < NN) ? n0 + 0 : NN - 1) * EE;
  const float* ep1 = embed + (long)((n0 + 1 < NN) ? n0 + 1 : NN - 1) * EE;
  const float* ep2 = embed + (long)((n0 + 2 < NN) ? n0 + 2 : NN - 1) * EE;
  const float* ep3 = embed + (long)((n0 + 3 < NN) ? n0 + 3 : NN - 1) * EE;
  float m0 = (n0 + 0 > 0 && n0 + 0 < NN) ? 1.0f : 0.0f;
  float m1 = (n0 + 1 > 0 && n0 + 1 < NN) ? 1.0f : 0.0f;
  float m2 = (n0 + 2 > 0 && n0 + 2 < NN) ? 1.0f : 0.0f;
  float m3 = (n0 + 3 > 0 && n0 + 3 < NN) ? 1.0f : 0.0f;
  float a0 = 0.0f, a1 = 0.0f, a2 = 0.0f, a3 = 0.0f;
  for (int e = 0; e < EE; e++) {
    float wv = W_enc[((long)(h * EE + e)) * EE + f];
    a0 += ep0[e] * wv; a1 += ep1[e] * wv;
    a2 += ep2[e] * wv; a3 += ep3[e] * wv;
  }
  a0 *= m0; a1 *= m1; a2 *= m2; a3 *= m3;
  if (n0 + 0 < NN) Wh[((long)(h * NN + n0 + 0)) * EE + f] = a0;
  if (n0 + 1 < NN) Wh[((long)(h * NN + n0 + 1)) * EE + f] = a1;
  if (n0 + 2 < NN) Wh[((long)(h * NN + n0 + 2)) * EE + f] = a2;
  if (n0 + 3 < NN) Wh[((long)(h * NN + n0 + 3)) * EE + f] = a3;
  float asv = a_src[h * EE + f];
  float adv = a_dst[h * EE + f];
  red[0][f] = a0 * asv; red[1][f] = a0 * adv;
  red[2][f] = a1 * asv; red[3][f] = a1 * adv;
  red[4][f] = a2 * asv; red[5][f] = a2 * adv;
  red[6][f] = a3 * asv; red[7][f] = a3 * adv;
  __syncthreads();
  for (int s = 64; s > 0; s >>= 1) {
    if (f < s) {
#pragma unroll
      for (int k = 0; k < 8; k++) red[k][f] += red[k][f + s];
    }
    __syncthreads();
  }
  if (f < 4) {
    int n = n0 + f;
    if (n < NN) {
      float v1 = red[2 * f][0];
      float v2 = red[2 * f + 1][0];
      f1[h * NN + n] = v1;
      f2[h * NN + n] = v2;
      if (n < LL) {
        ef1hi[h * LL + n] = expf(v1);
        ef1lo[h * LL + n] = expf(AL * v1);
      }
    }
  }
}

// ---- K2: counting rank + pstar, with k_w2 fused in (blocks 32..47) --------
__global__ void k_rankw2(const float* __restrict__ f2, const float* __restrict__ f1,
                         const float* __restrict__ W_dec, const float* __restrict__ a_vec,
                         int* __restrict__ jsort, float* __restrict__ elo,
                         float* __restrict__ ehi, int* __restrict__ pstar,
                         float* __restrict__ w2) {
  int gx = blockIdx.x;
  int t = threadIdx.x;   // 128
  if (gx >= 32) {
    int idx = gx - 32;          // 0..15
    int h = idx >> 2;
    int k = (idx & 3) * 128 + t;
    const float4* wp = (const float4*)&W_dec[(long)(h * HE + k) * DD];
    const float4* ap = (const float4*)&a_vec[h * DD];
    float s = 0.0f;
    for (int d = 0; d < DD / 4; d++) {
      float4 wv = wp[d];
      float4 av = ap[d];
      s += wv.x * av.x + wv.y * av.y + wv.z * av.z + wv.w * av.w;
    }
    w2[h * HE + k] = s;
    return;
  }
  __shared__ float key[LL];
  int h = gx & 3;
  int blk = gx >> 2;  // 0..7
  for (int q = t; q < LL; q += 128) key[q] = f2[h * NN + q];
  __syncthreads();
  int j0 = blk * 128 + t;
  float kv = key[j0];
  float tg = -f1[h * NN + j0];
  int rank = 0, cnt2 = 0;
  for (int q = 0; q < LL; q += 4) {
    float4 k4 = *(const float4*)&key[q];
    rank += ((k4.x < kv) || (k4.x == kv && (q + 0) < j0)) ? 1 : 0;
    rank += ((k4.y < kv) || (k4.y == kv && (q + 1) < j0)) ? 1 : 0;
    rank += ((k4.z < kv) || (k4.z == kv && (q + 2) < j0)) ? 1 : 0;
    rank += ((k4.w < kv) || (k4.w == kv && (q + 3) < j0)) ? 1 : 0;
    cnt2 += (k4.x < tg) ? 1 : 0;
    cnt2 += (k4.y < tg) ? 1 : 0;
    cnt2 += (k4.z < tg) ? 1 : 0;
    cnt2 += (k4.w < tg) ? 1 : 0;
  }
  jsort[h * LL + rank] = j0;
  elo[h * LL + rank] = expf(AL * kv);
  ehi[h * LL + rank] = expf(kv);
  pstar[h * LL + j0] = cnt2;
}

// ---- K3: FUSED chunk totals + exclusive scan (intra-block, no fences) -----
// one block per (bh, feature-half): 128 blocks x 1024 threads.
// 16 chunk-groups x 8 chunks; register-held totals; one barrier; LDS scan.
__global__ __launch_bounds__(1024) void k_scan(
    const int* __restrict__ data, const int* __restrict__ jsort,
    const float* __restrict__ elo, const float* __restrict__ ehi,
    const float* __restrict__ Wh,
    float* __restrict__ SnapLo, float* __restrict__ SnapHi,
    float* __restrict__ SnapLoS, float* __restrict__ SnapHiS) {
  __shared__ float glo[16][64];
  __shared__ float ghi[16][64];
  __shared__ float gsl[16];
  __shared__ float gsh[16];
  int bh = blockIdx.x >> 1;
  int half = blockIdx.x & 1;
  int b = bh >> 2;
  int h = bh & 3;
  int t = threadIdx.x;      // 1024
  int cg = t >> 6;          // 0..15 chunk group
  int fl = t & 63;
  int f = fl + half * 64;
  float tl[8], th[8], sla[8], sha[8];
#pragma unroll
  for (int k = 0; k < 8; k++) {
    int c = cg * 8 + k;
    int q0 = c * SS;
    int4 ja = *(const int4*)&jsort[h * LL + q0];
    int4 jb = *(const int4*)&jsort[h * LL + q0 + 4];
    float4 ea = *(const float4*)&elo[h * LL + q0];
    float4 eb = *(const float4*)&elo[h * LL + q0 + 4];
    float4 ha = *(const float4*)&ehi[h * LL + q0];
    float4 hb = *(const float4*)&ehi[h * LL + q0 + 4];
    int jarr[8] = {ja.x, ja.y, ja.z, ja.w, jb.x, jb.y, jb.z, jb.w};
    float wla[8] = {ea.x, ea.y, ea.z, ea.w, eb.x, eb.y, eb.z, eb.w};
    float wha[8] = {ha.x, ha.y, ha.z, ha.w, hb.x, hb.y, hb.z, hb.w};
    float al = 0.0f, ah = 0.0f, sl = 0.0f, sh = 0.0f;
#pragma unroll
    for (int r = 0; r < SS; r++) {
      if (data[b * LL + jarr[r]] != 0) {
        float v = Wh[((long)(h * NN + jarr[r])) * EE + f];
        al += wla[r] * v; ah += wha[r] * v;
        sl += wla[r]; sh += wha[r];
      }
    }
    tl[k] = al; th[k] = ah; sla[k] = sl; sha[k] = sh;
  }
  float gl = 0.0f, gh = 0.0f, gs_l = 0.0f, gs_h = 0.0f;
#pragma unroll
  for (int k = 0; k < 8; k++) { gl += tl[k]; gh += th[k]; gs_l += sla[k]; gs_h += sha[k]; }
  glo[cg][fl] = gl;
  ghi[cg][fl] = gh;
  if (fl == 0 && half == 0) { gsl[cg] = gs_l; gsh[cg] = gs_h; }
  __syncthreads();
  float gpl = 0.0f, gph = 0.0f;
#pragma unroll
  for (int g = 0; g < 16; g++) {
    if (g < cg) { gpl += glo[g][fl]; gph += ghi[g][fl]; }
  }
  float rl = gpl, rh = gph;
#pragma unroll
  for (int k = 0; k < 8; k++) {
    long o = (long)(bh * C1 + cg * 8 + k);
    SnapLo[o * EE + f] = rl;
    SnapHi[o * EE + f] = rh;
    rl += tl[k]; rh += th[k];
  }
  if (cg == 15) {
    long oc = (long)(bh * C1 + CC);
    SnapLo[oc * EE + f] = rl;
    SnapHi[oc * EE + f] = rh;
  }
  if (fl == 0 && half == 0) {
    float spl = 0.0f, sph = 0.0f;
#pragma unroll
    for (int g = 0; g < 16; g++) {
      if (g < cg) { spl += gsl[g]; sph += gsh[g]; }
    }
#pragma unroll
    for (int k = 0; k < 8; k++) {
      long o = (long)(bh * C1 + cg * 8 + k);
      SnapLoS[o] = spl;
      SnapHiS[o] = sph;
      spl += sla[k]; sph += sha[k];
    }
    if (cg == 15) {
      SnapLoS[(long)bh * C1 + CC] = spl;
      SnapHiS[(long)bh * C1 + CC] = sph;
    }
  }
}

// ---- K6: 4 waves/block, wave-per-row: prefix-attn -> LN -> elu -> wrow ----
__global__ __launch_bounds__(256) void k_row(
    const int* __restrict__ data, const float* __restrict__ Wh,
    const int* __restrict__ pstar, const int* __restrict__ jsort,
    const float* __restrict__ elo, const float* __restrict__ ehi,
    const float* __restrict__ ef1hi, const float* __restrict__ ef1lo,
    const float* __restrict__ SnapLo, const float* __restrict__ SnapHi,
    const float* __restrict__ SnapLoS, const float* __restrict__ SnapHiS,
    const float* __restrict__ g_enc, const float* __restrict__ b_enc,
    const float* __restrict__ w2,
    __hip_bfloat16* __restrict__ enc4, float* __restrict__ wrow) {
  int i = blockIdx.x * 4 + (threadIdx.x >> 6);
  int b = blockIdx.y;
  int t = threadIdx.x & 63;   // lane; features 2t, 2t+1
  if (data[b * LL + i] == 0) {
    if (t < HH) wrow[(b * HH + t) * LL + i] = 0.0f;
    return;
  }
  float x0[HH];
  float x1[HH];
#pragma unroll
  for (int h = 0; h < HH; h++) {
    int p = pstar[h * LL + i];
    int c = p / SS;
    int bh = b * HH + h;
    long o = (long)(bh * C1 + c);
    float2 rl = *(const float2*)&SnapLo[o * EE + 2 * t];
    float2 rh = *(const float2*)&SnapHi[o * EE + 2 * t];
    float rls = SnapLoS[o];
    float rhs = SnapHiS[o];
    int q0 = c * SS;
    int np = p - q0;
#pragma unroll
    for (int r = 0; r < 7; r++) {
      if (r < np) {
        int j = jsort[h * LL + q0 + r];
        if (data[b * LL + j] != 0) {
          float wl = elo[h * LL + q0 + r];
          float wh2 = ehi[h * LL + q0 + r];
          float2 v = *(const float2*)&Wh[((long)(h * NN + j)) * EE + 2 * t];
          rl.x += wl * v.x; rl.y += wl * v.y;
          rh.x += wh2 * v.x; rh.y += wh2 * v.y;
          rls += wl; rhs += wh2;
        }
      }
    }
    long ot = (long)(bh * C1 + CC);
    float2 Th = *(const float2*)&SnapHi[ot * EE + 2 * t];
    float Ths = SnapHiS[ot];
    float eh = ef1hi[h * LL + i];
    float el = ef1lo[h * LL + i];
    float den = 1.0f / (eh * (Ths - rhs) + el * rls);
    float v0 = (eh * (Th.x - rh.x) + el * rl.x) * den;
    float v1 = (eh * (Th.y - rh.y) + el * rl.y) * den;
    x0[h] = (v0 > 0.0f) ? v0 : (expf(v0) - 1.0f);
    x1[h] = (v1 > 0.0f) ? v1 : (expf(v1) - 1.0f);
  }
  float loc = 0.0f;
#pragma unroll
  for (int h = 0; h < HH; h++) loc += x0[h] + x1[h];
#pragma unroll
  for (int s = 1; s < 64; s <<= 1) loc += __shfl_xor(loc, s, 64);
  float mu = loc * (1.0f / 512.0f);
  float q2 = 0.0f;
#pragma unroll
  for (int h = 0; h < HH; h++) {
    float d0 = x0[h] - mu;
    float d1 = x1[h] - mu;
    q2 += d0 * d0 + d1 * d1;
  }
#pragma unroll
  for (int s = 1; s < 64; s <<= 1) q2 += __shfl_xor(q2, s, 64);
  float inv = 1.0f / (sqrtf(q2 * (1.0f / 511.0f)) + EPSV);
  float e40[HH];
  float e41[HH];
  long rowo = ((long)(b * LL + i)) * HE;
#pragma unroll
  for (int h = 0; h < HH; h++) {
    float2 g = *(const float2*)&g_enc[h * EE + 2 * t];
    float2 bb = *(const float2*)&b_enc[h * EE + 2 * t];
    float v0 = g.x * (x0[h] - mu) * inv + bb.x;
    float v1 = g.y * (x1[h] - mu) * inv + bb.y;
    e40[h] = (v0 > 0.0f) ? v0 : (expf(v0) - 1.0f);
    e41[h] = (v1 > 0.0f) ? v1 : (expf(v1) - 1.0f);
    __hip_bfloat162 pk;
    pk.x = __float2bfloat16(e40[h]);
    pk.y = __float2bfloat16(e41[h]);
    *(__hip_bfloat162*)&enc4[rowo + h * EE + 2 * t] = pk;
  }
  float p0 = 0.0f, p1 = 0.0f, p2 = 0.0f, p3 = 0.0f;
#pragma unroll
  for (int h = 0; h < HH; h++) {
    float2 wA = *(const float2*)&w2[0 * HE + h * EE + 2 * t];
    float2 wB = *(const float2*)&w2[1 * HE + h * EE + 2 * t];
    float2 wC = *(const float2*)&w2[2 * HE + h * EE + 2 * t];
    float2 wD = *(const float2*)&w2[3 * HE + h * EE + 2 * t];
    p0 += e40[h] * wA.x + e41[h] * wA.y;
    p1 += e40[h] * wB.x + e41[h] * wB.y;
    p2 += e40[h] * wC.x + e41[h] * wC.y;
    p3 += e40[h] * wD.x + e41[h] * wD.y;
  }
#pragma unroll
  for (int s = 1; s < 64; s <<= 1) {
    p0 += __shfl_xor(p0, s, 64);
    p1 += __shfl_xor(p1, s, 64);
    p2 += __shfl_xor(p2, s, 64);
    p3 += __shfl_xor(p3, s, 64);
  }
  if (t < HH) {
    float g = (t == 0) ? p0 : (t == 1) ? p1 : (t == 2) ? p2 : p3;
    if (g < 0.0f) g *= AL;
    wrow[(b * HH + t) * LL + i] = expf(g);
  }
}

// ---- K7: register-accumulated weighted row sums (512 blocks) --------------
__global__ __launch_bounds__(256) void k_acc(
    const int* __restrict__ data, const __hip_bfloat16* __restrict__ enc4,
    const float* __restrict__ wrow, float* __restrict__ Upart) {
  int c = blockIdx.x;    // 0..31 chunks of 32 rows
  int b = blockIdx.y;
  int t = threadIdx.x;   // 256; features 2t, 2t+1 of HE
  float a00 = 0.0f, a01 = 0.0f, a10 = 0.0f, a11 = 0.0f;
  float a20 = 0.0f, a21 = 0.0f, a30 = 0.0f, a31 = 0.0f;
#pragma unroll 4
  for (int r = 0; r < 32; r++) {
    int i = c * 32 + r;
    if (data[b * LL + i] == 0) continue;
    float w0 = wrow[(b * HH + 0) * LL + i];
    float w1 = wrow[(b * HH + 1) * LL + i];
    float w2v = wrow[(b * HH + 2) * LL + i];
    float w3 = wrow[(b * HH + 3) * LL + i];
    __hip_bfloat162 pk = *(const __hip_bfloat162*)&enc4[((long)(b * LL + i)) * HE + 2 * t];
    float e0 = __bfloat162float(pk.x);
    float e1 = __bfloat162float(pk.y);
    a00 += w0 * e0; a01 += w0 * e1;
    a10 += w1 * e0; a11 += w1 * e1;
    a20 += w2v * e0; a21 += w2v * e1;
    a30 += w3 * e0; a31 += w3 * e1;
  }
  long base = (long)(b * 32 + c) * (HH * HE);
  float2 s2;
  s2.x = a00; s2.y = a01; *(float2*)&Upart[base + 0 * HE + 2 * t] = s2;
  s2.x = a10; s2.y = a11; *(float2*)&Upart[base + 1 * HE + 2 * t] = s2;
  s2.x = a20; s2.y = a21; *(float2*)&Upart[base + 2 * HE + 2 * t] = s2;
  s2.x = a30; s2.y = a31; *(float2*)&Upart[base + 3 * HE + 2 * t] = s2;
}

// ---- K8: fused finisher: Upart-sum + z + U*W_dec + LN + V + o1 + o2 -------
__global__ __launch_bounds__(1024) void k_fin(
    const float* __restrict__ Upart, const float* __restrict__ wrow,
    const float* __restrict__ W_dec,
    const float* __restrict__ g_dec, const float* __restrict__ b_dec,
    const float* __restrict__ V_w, const float* __restrict__ V_b,
    const float* __restrict__ o1_w, const float* __restrict__ o1_b,
    const float* __restrict__ o2_w, const float* __restrict__ o2_b,
    float* __restrict__ out) {
  __shared__ float Ut[HH * HE];     // 8 KB scaled U (incl. 0.25/(1+z))
  __shared__ float zr[4][256];      // 4 KB z partials
  __shared__ float zs[4];
  __shared__ float red8[8][DD];     // 4 KB matvec partials
  __shared__ float red[DD];
  __shared__ float xs[DD];
  int b = blockIdx.x;
  int t = threadIdx.x;     // 1024
  int rg = t >> 8;         // 0..3
  int tt = t & 255;
  float zp = wrow[(b * HH + rg) * LL + tt]
           + wrow[(b * HH + rg) * LL + tt + 256]
           + wrow[(b * HH + rg) * LL + tt + 512]
           + wrow[(b * HH + rg) * LL + tt + 768];
  zr[rg][tt] = zp;
  float us0 = 0.0f, us1 = 0.0f;
#pragma unroll 8
  for (int c = 0; c < 32; c++) {
    const float* p = &Upart[(long)(b * 32 + c) * (HH * HE)];
    us0 += p[t];
    us1 += p[t + 1024];
  }
  __syncthreads();
  int wid = t >> 6;
  int lane = t & 63;
  if (wid < 4) {
    float s = zr[wid][lane] + zr[wid][lane + 64] + zr[wid][lane + 128] + zr[wid][lane + 192];
#pragma unroll
    for (int d = 1; d < 64; d <<= 1) s += __shfl_xor(s, d, 64);
    if (lane == 0) zs[wid] = 0.25f / (1.0f + s);
  }
  __syncthreads();
  Ut[t] = us0 * zs[t >> 9];
  Ut[t + 1024] = us1 * zs[(t + 1024) >> 9];
  __syncthreads();
  int f = t & 127;
  int kg = t >> 7;   // 0..7
  {
    float s = 0.0f;
    int k0 = kg * 256;
#pragma unroll 8
    for (int kk = k0; kk < k0 + 256; kk++) {
      s += Ut[kk] * W_dec[(long)kk * DD + f];
    }
    red8[kg][f] = s;
  }
  __syncthreads();
  float dec = 0.0f;
  if (t < DD) {
#pragma unroll
    for (int g = 0; g < 8; g++) dec += red8[g][t];
    red[t] = dec;
  }
  __syncthreads();
  for (int s = 64; s > 0; s >>= 1) {
    if (t < s) red[t] += red[t + s];
    __syncthreads();
  }
  float mu = red[0] / 128.0f;
  __syncthreads();
  float dd = 0.0f;
  if (t < DD) { dd = dec - mu; red[t] = dd * dd; }
  __syncthreads();
  for (int s = 64; s > 0; s >>= 1) {
    if (t < s) red[t] += red[t + s];
    __syncthreads();
  }
  float sd = sqrtf(red[0] / 127.0f);
  __syncthreads();
  if (t < DD) {
    float v = g_dec[t] * dd / (sd + EPSV) + b_dec[t];
    if (v < 0.0f) v = 0.0f;
    xs[t] = v;
  }
  __syncthreads();
  {
    float s = 0.0f;
    int k0 = kg * 16;
#pragma unroll
    for (int k = k0; k < k0 + 16; k++) s += xs[k] * V_w[k * DD + f];
    red8[kg][f] = s;
  }
  __syncthreads();
  float xv = 0.0f;
  if (t < DD) {
#pragma unroll
    for (int g = 0; g < 8; g++) xv += red8[g][t];
    xv += V_b[t];
  }
  __syncthreads();
  if (t < DD) xs[t] = xv;
  __syncthreads();
  {
    float s = 0.0f;
    int k0 = kg * 16;
#pragma unroll
    for (int k = k0; k < k0 + 16; k++) s += xs[k] * o1_w[k * DD + f];
    red8[kg][f] = s;
  }
  __syncthreads();
  if (t < DD) {
    float hv = 0.0f;
#pragma unroll
    for (int g = 0; g < 8; g++) hv += red8[g][t];
    hv += o1_b[t];
    if (hv < 0.0f) hv = 0.0f;
    red[t] = hv * o2_w[t];
  }
  __syncthreads();
  for (int s = 64; s > 0; s >>= 1) {
    if (t < s) red[t] += red[t + s];
    __syncthreads();
  }
  if (t == 0) out[b] = red[0] + o2_b[0];
}

extern "C" void kernel_launch(void* const* d_in, const int* in_sizes, int n_in,
                              void* d_out, int out_size, void* d_ws, size_t ws_size,
                              hipStream_t stream) {
  const int* data    = (const int*)d_in[0];
  const float* embed  = (const float*)d_in[1];
  const float* W_enc  = (const float*)d_in[2];
  const float* a_esrc = (const float*)d_in[3];
  const float* a_edst = (const float*)d_in[4];
  const float* g_enc  = (const float*)d_in[5];
  const float* b_enc  = (const float*)d_in[6];
  const float* W_dec  = (const float*)d_in[7];
  const float* a_ddst = (const float*)d_in[9];
  const float* g_dec  = (const float*)d_in[10];
  const float* b_dec  = (const float*)d_in[11];
  const float* V_w    = (const float*)d_in[12];
  const float* V_b    = (const float*)d_in[13];
  const float* o1_w   = (const float*)d_in[14];
  const float* o1_b   = (const float*)d_in[15];
  const float* o2_w   = (const float*)d_in[16];
  const float* o2_b   = (const float*)d_in[17];
  float* out = (float*)d_out;               // fp32 output

  float* w = (float*)d_ws;
  float* Wh    = w + O_WH;
  float* f1    = w + O_F1;
  float* f2    = w + O_F2;
  float* elo   = w + O_ELO;
  float* ehi   = w + O_EHI;
  float* ef1hi = w + O_EF1H;
  float* ef1lo = w + O_EF1L;
  float* w2    = w + O_W2;
  float* SnapLo  = w + O_SLO;
  float* SnapHi  = w + O_SHI;
  float* SnapLoS = w + O_SLOS;
  float* SnapHiS = w + O_SHIS;
  float* wrow  = w + O_WR;
  float* Upart = w + O_UP;
  int* jsort   = (int*)(w + O_JS);
  int* pstar   = (int*)(w + O_PS);
  __hip_bfloat16* enc4 = (__hip_bfloat16*)(w + O_E4);

  VGNN_27049704030896_kernel<<<dim3((NN + 3) / 4, HH), 128, 0, stream>>>(
      embed, W_enc, a_esrc, a_edst, Wh, f1, f2, ef1hi, ef1lo);
  k_rankw2<<<48, 128, 0, stream>>>(f2, f1, W_dec, a_ddst,
                                   jsort, elo, ehi, pstar, w2);
  k_scan<<<BB * HH * 2, 1024, 0, stream>>>(data, jsort, elo, ehi, Wh,
                                           SnapLo, SnapHi, SnapLoS, SnapHiS);
  k_row <<<dim3(LL / 4, BB), 256, 0, stream>>>(data, Wh, pstar, jsort, elo, ehi,
                                               ef1hi, ef1lo, SnapLo, SnapHi,
                                               SnapLoS, SnapHiS, g_enc, b_enc, w2,
                                               enc4, wrow);
  k_acc <<<dim3(32, BB), 256, 0, stream>>>(data, enc4, wrow, Upart);
  k_fin <<<BB, 1024, 0, stream>>>(Upart, wrow, W_dec,
                                  g_dec, b_dec, V_w, V_b,
                                  o1_w, o1_b, o2_w, o2_b, out);
}

// Round 7
// 207.771 us; speedup vs baseline: 3.2899x; 1.0449x over previous
//
#include <hip/hip_runtime.h>
#include <hip/hip_bf16.h>

#define BB 16
#define LL 1024
#define EE 128
#define HH 4
#define DD 128
#define NN 1025
#define HE 512
#define AL 0.2f
#define EPSV 1e-6f
#define SS 8
#define CC 128
#define C1 129

// workspace float offsets (footprint unchanged vs verified layout).
#define O_WH   0
#define O_F1   524800
#define O_F2   528900
#define O_ELO  537096
#define O_EHI  541192
#define O_EF1H 545288
#define O_EF1L 549384
#define O_W2   553480
#define O_SLO  555528
#define O_SHI  1612296
#define O_SLOS 2669064
#define O_SHIS 2677320
#define O_WR   2685576
#define O_UP   2751112
#define O_JS   3799688
#define O_PS   3803784
#define O_E4   3807880

// ---- K1: Wh + f1/f2 + exp tables; 4 rows/block for W_enc L2 reuse ---------
__global__ void VGNN_27049704030896_kernel(const float* __restrict__ embed,
                                           const float* __restrict__ W_enc,
                                           const float* __restrict__ a_src,
                                           const float* __restrict__ a_dst,
                                           float* __restrict__ Wh,
                                           float* __restrict__ f1,
                                           float* __restrict__ f2,
                                           float* __restrict__ ef1hi,
                                           float* __restrict__ ef1lo) {
  __shared__ float red[8][EE];
  int n0 = blockIdx.x * 4;
  int h = blockIdx.y;
  int f = threadIdx.x;   // 128
  const float* ep0 = embed + (long)((n0 + 0 < NN) ? n0 + 0 : NN - 1) * EE;
  const float* ep1 = embed + (long)((n0 + 1 < NN) ? n0 + 1 : NN - 1) * EE;
  const float* ep2 = embed + (long)((n0 + 2 < NN) ? n0 + 2 : NN - 1) * EE;
  const float* ep3 = embed + (long)((n0 + 3 < NN) ? n0 + 3 : NN - 1) * EE;
  float m0 = (n0 + 0 > 0 && n0 + 0 < NN) ? 1.0f : 0.0f;
  float m1 = (n0 + 1 > 0 && n0 + 1 < NN) ? 1.0f : 0.0f;
  float m2 = (n0 + 2 > 0 && n0 + 2 < NN) ? 1.0f : 0.0f;
  float m3 = (n0 + 3 > 0 && n0 + 3 < NN) ? 1.0f : 0.0f;
  float a0 = 0.0f, a1 = 0.0f, a2 = 0.0f, a3 = 0.0f;
  for (int e = 0; e < EE; e++) {
    float wv = W_enc[((long)(h * EE + e)) * EE + f];
    a0 += ep0[e] * wv; a1 += ep1[e] * wv;
    a2 += ep2[e] * wv; a3 += ep3[e] * wv;
  }
  a0 *= m0; a1 *= m1; a2 *= m2; a3 *= m3;
  if (n0 + 0 < NN) Wh[((long)(h * NN + n0 + 0)) * EE + f] = a0;
  if (n0 + 1 < NN) Wh[((long)(h * NN + n0 + 1)) * EE + f] = a1;
  if (n0 + 2 < NN) Wh[((long)(h * NN + n0 + 2)) * EE + f] = a2;
  if (n0 + 3 < NN) Wh[((long)(h * NN + n0 + 3)) * EE + f] = a3;
  float asv = a_src[h * EE + f];
  float adv = a_dst[h * EE + f];
  red[0][f] = a0 * asv; red[1][f] = a0 * adv;
  red[2][f] = a1 * asv; red[3][f] = a1 * adv;
  red[4][f] = a2 * asv; red[5][f] = a2 * adv;
  red[6][f] = a3 * asv; red[7][f] = a3 * adv;
  __syncthreads();
  for (int s = 64; s > 0; s >>= 1) {
    if (f < s) {
#pragma unroll
      for (int k = 0; k < 8; k++) red[k][f] += red[k][f + s];
    }
    __syncthreads();
  }
  if (f < 4) {
    int n = n0 + f;
    if (n < NN) {
      float v1 = red[2 * f][0];
      float v2 = red[2 * f + 1][0];
      f1[h * NN + n] = v1;
      f2[h * NN + n] = v2;
      if (n < LL) {
        ef1hi[h * LL + n] = __expf(v1);
        ef1lo[h * LL + n] = __expf(AL * v1);
      }
    }
  }
}

// ---- K2: counting rank + pstar, with k_w2 fused in (blocks 32..47) --------
__global__ void k_rankw2(const float* __restrict__ f2, const float* __restrict__ f1,
                         const float* __restrict__ W_dec, const float* __restrict__ a_vec,
                         int* __restrict__ jsort, float* __restrict__ elo,
                         float* __restrict__ ehi, int* __restrict__ pstar,
                         float* __restrict__ w2) {
  int gx = blockIdx.x;
  int t = threadIdx.x;   // 128
  if (gx >= 32) {
    int idx = gx - 32;          // 0..15
    int h = idx >> 2;
    int k = (idx & 3) * 128 + t;
    const float4* wp = (const float4*)&W_dec[(long)(h * HE + k) * DD];
    const float4* ap = (const float4*)&a_vec[h * DD];
    float s = 0.0f;
    for (int d = 0; d < DD / 4; d++) {
      float4 wv = wp[d];
      float4 av = ap[d];
      s += wv.x * av.x + wv.y * av.y + wv.z * av.z + wv.w * av.w;
    }
    w2[h * HE + k] = s;
    return;
  }
  __shared__ float key[LL];
  int h = gx & 3;
  int blk = gx >> 2;  // 0..7
  for (int q = t; q < LL; q += 128) key[q] = f2[h * NN + q];
  __syncthreads();
  int j0 = blk * 128 + t;
  float kv = key[j0];
  float tg = -f1[h * NN + j0];
  int rank = 0, cnt2 = 0;
  for (int q = 0; q < LL; q += 4) {
    float4 k4 = *(const float4*)&key[q];
    rank += ((k4.x < kv) || (k4.x == kv && (q + 0) < j0)) ? 1 : 0;
    rank += ((k4.y < kv) || (k4.y == kv && (q + 1) < j0)) ? 1 : 0;
    rank += ((k4.z < kv) || (k4.z == kv && (q + 2) < j0)) ? 1 : 0;
    rank += ((k4.w < kv) || (k4.w == kv && (q + 3) < j0)) ? 1 : 0;
    cnt2 += (k4.x < tg) ? 1 : 0;
    cnt2 += (k4.y < tg) ? 1 : 0;
    cnt2 += (k4.z < tg) ? 1 : 0;
    cnt2 += (k4.w < tg) ? 1 : 0;
  }
  jsort[h * LL + rank] = j0;
  elo[h * LL + rank] = __expf(AL * kv);
  ehi[h * LL + rank] = __expf(kv);
  pstar[h * LL + j0] = cnt2;
}

// ---- K3: FUSED chunk totals + exclusive scan (intra-block, no fences) -----
__global__ __launch_bounds__(1024) void k_scan(
    const int* __restrict__ data, const int* __restrict__ jsort,
    const float* __restrict__ elo, const float* __restrict__ ehi,
    const float* __restrict__ Wh,
    float* __restrict__ SnapLo, float* __restrict__ SnapHi,
    float* __restrict__ SnapLoS, float* __restrict__ SnapHiS) {
  __shared__ float glo[16][64];
  __shared__ float ghi[16][64];
  __shared__ float gsl[16];
  __shared__ float gsh[16];
  int bh = blockIdx.x >> 1;
  int half = blockIdx.x & 1;
  int b = bh >> 2;
  int h = bh & 3;
  int t = threadIdx.x;      // 1024
  int cg = t >> 6;          // 0..15 chunk group
  int fl = t & 63;
  int f = fl + half * 64;
  float tl[8], th[8], sla[8], sha[8];
#pragma unroll
  for (int k = 0; k < 8; k++) {
    int c = cg * 8 + k;
    int q0 = c * SS;
    int4 ja = *(const int4*)&jsort[h * LL + q0];
    int4 jb = *(const int4*)&jsort[h * LL + q0 + 4];
    float4 ea = *(const float4*)&elo[h * LL + q0];
    float4 eb = *(const float4*)&elo[h * LL + q0 + 4];
    float4 ha = *(const float4*)&ehi[h * LL + q0];
    float4 hb = *(const float4*)&ehi[h * LL + q0 + 4];
    int jarr[8] = {ja.x, ja.y, ja.z, ja.w, jb.x, jb.y, jb.z, jb.w};
    float wla[8] = {ea.x, ea.y, ea.z, ea.w, eb.x, eb.y, eb.z, eb.w};
    float wha[8] = {ha.x, ha.y, ha.z, ha.w, hb.x, hb.y, hb.z, hb.w};
    float al = 0.0f, ah = 0.0f, sl = 0.0f, sh = 0.0f;
#pragma unroll
    for (int r = 0; r < SS; r++) {
      if (data[b * LL + jarr[r]] != 0) {
        float v = Wh[((long)(h * NN + jarr[r])) * EE + f];
        al += wla[r] * v; ah += wha[r] * v;
        sl += wla[r]; sh += wha[r];
      }
    }
    tl[k] = al; th[k] = ah; sla[k] = sl; sha[k] = sh;
  }
  float gl = 0.0f, gh = 0.0f, gs_l = 0.0f, gs_h = 0.0f;
#pragma unroll
  for (int k = 0; k < 8; k++) { gl += tl[k]; gh += th[k]; gs_l += sla[k]; gs_h += sha[k]; }
  glo[cg][fl] = gl;
  ghi[cg][fl] = gh;
  if (fl == 0 && half == 0) { gsl[cg] = gs_l; gsh[cg] = gs_h; }
  __syncthreads();
  float gpl = 0.0f, gph = 0.0f;
#pragma unroll
  for (int g = 0; g < 16; g++) {
    if (g < cg) { gpl += glo[g][fl]; gph += ghi[g][fl]; }
  }
  float rl = gpl, rh = gph;
#pragma unroll
  for (int k = 0; k < 8; k++) {
    long o = (long)(bh * C1 + cg * 8 + k);
    SnapLo[o * EE + f] = rl;
    SnapHi[o * EE + f] = rh;
    rl += tl[k]; rh += th[k];
  }
  if (cg == 15) {
    long oc = (long)(bh * C1 + CC);
    SnapLo[oc * EE + f] = rl;
    SnapHi[oc * EE + f] = rh;
  }
  if (fl == 0 && half == 0) {
    float spl = 0.0f, sph = 0.0f;
#pragma unroll
    for (int g = 0; g < 16; g++) {
      if (g < cg) { spl += gsl[g]; sph += gsh[g]; }
    }
#pragma unroll
    for (int k = 0; k < 8; k++) {
      long o = (long)(bh * C1 + cg * 8 + k);
      SnapLoS[o] = spl;
      SnapHiS[o] = sph;
      spl += sla[k]; sph += sha[k];
    }
    if (cg == 15) {
      SnapLoS[(long)bh * C1 + CC] = spl;
      SnapHiS[(long)bh * C1 + CC] = sph;
    }
  }
}

// ---- K6: 4 waves/block, wave-per-row; scalar-hoisted p; fast exp ----------
__global__ __launch_bounds__(256) void k_row(
    const int* __restrict__ data, const float* __restrict__ Wh,
    const int* __restrict__ pstar, const int* __restrict__ jsort,
    const float* __restrict__ elo, const float* __restrict__ ehi,
    const float* __restrict__ ef1hi, const float* __restrict__ ef1lo,
    const float* __restrict__ SnapLo, const float* __restrict__ SnapHi,
    const float* __restrict__ SnapLoS, const float* __restrict__ SnapHiS,
    const float* __restrict__ g_enc, const float* __restrict__ b_enc,
    const float* __restrict__ w2,
    __hip_bfloat16* __restrict__ enc4, float* __restrict__ wrow) {
  int i = blockIdx.x * 4 + (threadIdx.x >> 6);
  int b = blockIdx.y;
  int t = threadIdx.x & 63;   // lane; features 2t, 2t+1
  if (data[b * LL + i] == 0) {
    if (t < HH) wrow[(b * HH + t) * LL + i] = 0.0f;
    return;
  }
  float x0[HH];
  float x1[HH];
#pragma unroll
  for (int h = 0; h < HH; h++) {
    // p is wave-uniform: hoist to SGPR so Snap scalar loads go down the
    // scalar path and the fixup-count branches are s_cbranch.
    int p = __builtin_amdgcn_readfirstlane(pstar[h * LL + i]);
    int c = p / SS;
    int bh = b * HH + h;
    long o = (long)(bh * C1 + c);
    float2 rl = *(const float2*)&SnapLo[o * EE + 2 * t];
    float2 rh = *(const float2*)&SnapHi[o * EE + 2 * t];
    float rls = SnapLoS[o];
    float rhs = SnapHiS[o];
    int q0 = c * SS;
    int np = p - q0;
#pragma unroll
    for (int r = 0; r < 7; r++) {
      if (r < np) {
        int j = jsort[h * LL + q0 + r];
        if (data[b * LL + j] != 0) {
          float wl = elo[h * LL + q0 + r];
          float wh2 = ehi[h * LL + q0 + r];
          float2 v = *(const float2*)&Wh[((long)(h * NN + j)) * EE + 2 * t];
          rl.x += wl * v.x; rl.y += wl * v.y;
          rh.x += wh2 * v.x; rh.y += wh2 * v.y;
          rls += wl; rhs += wh2;
        }
      }
    }
    long ot = (long)(bh * C1 + CC);
    float2 Th = *(const float2*)&SnapHi[ot * EE + 2 * t];
    float Ths = SnapHiS[ot];
    float eh = ef1hi[h * LL + i];
    float el = ef1lo[h * LL + i];
    float den = 1.0f / (eh * (Ths - rhs) + el * rls);
    float v0 = (eh * (Th.x - rh.x) + el * rl.x) * den;
    float v1 = (eh * (Th.y - rh.y) + el * rl.y) * den;
    x0[h] = (v0 > 0.0f) ? v0 : (__expf(v0) - 1.0f);
    x1[h] = (v1 > 0.0f) ? v1 : (__expf(v1) - 1.0f);
  }
  float loc = 0.0f;
#pragma unroll
  for (int h = 0; h < HH; h++) loc += x0[h] + x1[h];
#pragma unroll
  for (int s = 1; s < 64; s <<= 1) loc += __shfl_xor(loc, s, 64);
  float mu = loc * (1.0f / 512.0f);
  float q2 = 0.0f;
#pragma unroll
  for (int h = 0; h < HH; h++) {
    float d0 = x0[h] - mu;
    float d1 = x1[h] - mu;
    q2 += d0 * d0 + d1 * d1;
  }
#pragma unroll
  for (int s = 1; s < 64; s <<= 1) q2 += __shfl_xor(q2, s, 64);
  float inv = 1.0f / (sqrtf(q2 * (1.0f / 511.0f)) + EPSV);
  float e40[HH];
  float e41[HH];
  long rowo = ((long)(b * LL + i)) * HE;
#pragma unroll
  for (int h = 0; h < HH; h++) {
    float2 g = *(const float2*)&g_enc[h * EE + 2 * t];
    float2 bb = *(const float2*)&b_enc[h * EE + 2 * t];
    float v0 = g.x * (x0[h] - mu) * inv + bb.x;
    float v1 = g.y * (x1[h] - mu) * inv + bb.y;
    e40[h] = (v0 > 0.0f) ? v0 : (__expf(v0) - 1.0f);
    e41[h] = (v1 > 0.0f) ? v1 : (__expf(v1) - 1.0f);
    __hip_bfloat162 pk;
    pk.x = __float2bfloat16(e40[h]);
    pk.y = __float2bfloat16(e41[h]);
    *(__hip_bfloat162*)&enc4[rowo + h * EE + 2 * t] = pk;
  }
  float p0 = 0.0f, p1 = 0.0f, p2 = 0.0f, p3 = 0.0f;
#pragma unroll
  for (int h = 0; h < HH; h++) {
    float2 wA = *(const float2*)&w2[0 * HE + h * EE + 2 * t];
    float2 wB = *(const float2*)&w2[1 * HE + h * EE + 2 * t];
    float2 wC = *(const float2*)&w2[2 * HE + h * EE + 2 * t];
    float2 wD = *(const float2*)&w2[3 * HE + h * EE + 2 * t];
    p0 += e40[h] * wA.x + e41[h] * wA.y;
    p1 += e40[h] * wB.x + e41[h] * wB.y;
    p2 += e40[h] * wC.x + e41[h] * wC.y;
    p3 += e40[h] * wD.x + e41[h] * wD.y;
  }
#pragma unroll
  for (int s = 1; s < 64; s <<= 1) {
    p0 += __shfl_xor(p0, s, 64);
    p1 += __shfl_xor(p1, s, 64);
    p2 += __shfl_xor(p2, s, 64);
    p3 += __shfl_xor(p3, s, 64);
  }
  if (t < HH) {
    float g = (t == 0) ? p0 : (t == 1) ? p1 : (t == 2) ? p2 : p3;
    if (g < 0.0f) g *= AL;
    wrow[(b * HH + t) * LL + i] = __expf(g);
  }
}

// ---- K7: register-accumulated weighted row sums (512 blocks) --------------
__global__ __launch_bounds__(256) void k_acc(
    const int* __restrict__ data, const __hip_bfloat16* __restrict__ enc4,
    const float* __restrict__ wrow, float* __restrict__ Upart) {
  int c = blockIdx.x;    // 0..31 chunks of 32 rows
  int b = blockIdx.y;
  int t = threadIdx.x;   // 256; features 2t, 2t+1 of HE
  float a00 = 0.0f, a01 = 0.0f, a10 = 0.0f, a11 = 0.0f;
  float a20 = 0.0f, a21 = 0.0f, a30 = 0.0f, a31 = 0.0f;
#pragma unroll 4
  for (int r = 0; r < 32; r++) {
    int i = c * 32 + r;
    if (data[b * LL + i] == 0) continue;
    float w0 = wrow[(b * HH + 0) * LL + i];
    float w1 = wrow[(b * HH + 1) * LL + i];
    float w2v = wrow[(b * HH + 2) * LL + i];
    float w3 = wrow[(b * HH + 3) * LL + i];
    __hip_bfloat162 pk = *(const __hip_bfloat162*)&enc4[((long)(b * LL + i)) * HE + 2 * t];
    float e0 = __bfloat162float(pk.x);
    float e1 = __bfloat162float(pk.y);
    a00 += w0 * e0; a01 += w0 * e1;
    a10 += w1 * e0; a11 += w1 * e1;
    a20 += w2v * e0; a21 += w2v * e1;
    a30 += w3 * e0; a31 += w3 * e1;
  }
  long base = (long)(b * 32 + c) * (HH * HE);
  float2 s2;
  s2.x = a00; s2.y = a01; *(float2*)&Upart[base + 0 * HE + 2 * t] = s2;
  s2.x = a10; s2.y = a11; *(float2*)&Upart[base + 1 * HE + 2 * t] = s2;
  s2.x = a20; s2.y = a21; *(float2*)&Upart[base + 2 * HE + 2 * t] = s2;
  s2.x = a30; s2.y = a31; *(float2*)&Upart[base + 3 * HE + 2 * t] = s2;
}

// ---- K8: fused finisher: Upart-sum + z + U*W_dec + LN + V + o1 + o2 -------
__global__ __launch_bounds__(1024) void k_fin(
    const float* __restrict__ Upart, const float* __restrict__ wrow,
    const float* __restrict__ W_dec,
    const float* __restrict__ g_dec, const float* __restrict__ b_dec,
    const float* __restrict__ V_w, const float* __restrict__ V_b,
    const float* __restrict__ o1_w, const float* __restrict__ o1_b,
    const float* __restrict__ o2_w, const float* __restrict__ o2_b,
    float* __restrict__ out) {
  __shared__ float Ut[HH * HE];     // 8 KB scaled U (incl. 0.25/(1+z))
  __shared__ float zr[4][256];      // 4 KB z partials
  __shared__ float zs[4];
  __shared__ float red8[8][DD];     // 4 KB matvec partials
  __shared__ float red[DD];
  __shared__ float xs[DD];
  int b = blockIdx.x;
  int t = threadIdx.x;     // 1024
  int rg = t >> 8;         // 0..3
  int tt = t & 255;
  float zp = wrow[(b * HH + rg) * LL + tt]
           + wrow[(b * HH + rg) * LL + tt + 256]
           + wrow[(b * HH + rg) * LL + tt + 512]
           + wrow[(b * HH + rg) * LL + tt + 768];
  zr[rg][tt] = zp;
  float us0 = 0.0f, us1 = 0.0f;
#pragma unroll 8
  for (int c = 0; c < 32; c++) {
    const float* p = &Upart[(long)(b * 32 + c) * (HH * HE)];
    us0 += p[t];
    us1 += p[t + 1024];
  }
  __syncthreads();
  int wid = t >> 6;
  int lane = t & 63;
  if (wid < 4) {
    float s = zr[wid][lane] + zr[wid][lane + 64] + zr[wid][lane + 128] + zr[wid][lane + 192];
#pragma unroll
    for (int d = 1; d < 64; d <<= 1) s += __shfl_xor(s, d, 64);
    if (lane == 0) zs[wid] = 0.25f / (1.0f + s);
  }
  __syncthreads();
  Ut[t] = us0 * zs[t >> 9];
  Ut[t + 1024] = us1 * zs[(t + 1024) >> 9];
  __syncthreads();
  int f = t & 127;
  int kg = t >> 7;   // 0..7
  {
    float s = 0.0f;
    int k0 = kg * 256;
#pragma unroll 8
    for (int kk = k0; kk < k0 + 256; kk++) {
      s += Ut[kk] * W_dec[(long)kk * DD + f];
    }
    red8[kg][f] = s;
  }
  __syncthreads();
  float dec = 0.0f;
  if (t < DD) {
#pragma unroll
    for (int g = 0; g < 8; g++) dec += red8[g][t];
    red[t] = dec;
  }
  __syncthreads();
  for (int s = 64; s > 0; s >>= 1) {
    if (t < s) red[t] += red[t + s];
    __syncthreads();
  }
  float mu = red[0] / 128.0f;
  __syncthreads();
  float dd = 0.0f;
  if (t < DD) { dd = dec - mu; red[t] = dd * dd; }
  __syncthreads();
  for (int s = 64; s > 0; s >>= 1) {
    if (t < s) red[t] += red[t + s];
    __syncthreads();
  }
  float sd = sqrtf(red[0] / 127.0f);
  __syncthreads();
  if (t < DD) {
    float v = g_dec[t] * dd / (sd + EPSV) + b_dec[t];
    if (v < 0.0f) v = 0.0f;
    xs[t] = v;
  }
  __syncthreads();
  {
    float s = 0.0f;
    int k0 = kg * 16;
#pragma unroll
    for (int k = k0; k < k0 + 16; k++) s += xs[k] * V_w[k * DD + f];
    red8[kg][f] = s;
  }
  __syncthreads();
  float xv = 0.0f;
  if (t < DD) {
#pragma unroll
    for (int g = 0; g < 8; g++) xv += red8[g][t];
    xv += V_b[t];
  }
  __syncthreads();
  if (t < DD) xs[t] = xv;
  __syncthreads();
  {
    float s = 0.0f;
    int k0 = kg * 16;
#pragma unroll
    for (int k = k0; k < k0 + 16; k++) s += xs[k] * o1_w[k * DD + f];
    red8[kg][f] = s;
  }
  __syncthreads();
  if (t < DD) {
    float hv = 0.0f;
#pragma unroll
    for (int g = 0; g < 8; g++) hv += red8[g][t];
    hv += o1_b[t];
    if (hv < 0.0f) hv = 0.0f;
    red[t] = hv * o2_w[t];
  }
  __syncthreads();
  for (int s = 64; s > 0; s >>= 1) {
    if (t < s) red[t] += red[t + s];
    __syncthreads();
  }
  if (t == 0) out[b] = red[0] + o2_b[0];
}

extern "C" void kernel_launch(void* const* d_in, const int* in_sizes, int n_in,
                              void* d_out, int out_size, void* d_ws, size_t ws_size,
                              hipStream_t stream) {
  const int* data    = (const int*)d_in[0];
  const float* embed  = (const float*)d_in[1];
  const float* W_enc  = (const float*)d_in[2];
  const float* a_esrc = (const float*)d_in[3];
  const float* a_edst = (const float*)d_in[4];
  const float* g_enc  = (const float*)d_in[5];
  const float* b_enc  = (const float*)d_in[6];
  const float* W_dec  = (const float*)d_in[7];
  const float* a_ddst = (const float*)d_in[9];
  const float* g_dec  = (const float*)d_in[10];
  const float* b_dec  = (const float*)d_in[11];
  const float* V_w    = (const float*)d_in[12];
  const float* V_b    = (const float*)d_in[13];
  const float* o1_w   = (const float*)d_in[14];
  const float* o1_b   = (const float*)d_in[15];
  const float* o2_w   = (const float*)d_in[16];
  const float* o2_b   = (const float*)d_in[17];
  float* out = (float*)d_out;               // fp32 output

  float* w = (float*)d_ws;
  float* Wh    = w + O_WH;
  float* f1    = w + O_F1;
  float* f2    = w + O_F2;
  float* elo   = w + O_ELO;
  float* ehi   = w + O_EHI;
  float* ef1hi = w + O_EF1H;
  float* ef1lo = w + O_EF1L;
  float* w2    = w + O_W2;
  float* SnapLo  = w + O_SLO;
  float* SnapHi  = w + O_SHI;
  float* SnapLoS = w + O_SLOS;
  float* SnapHiS = w + O_SHIS;
  float* wrow  = w + O_WR;
  float* Upart = w + O_UP;
  int* jsort   = (int*)(w + O_JS);
  int* pstar   = (int*)(w + O_PS);
  __hip_bfloat16* enc4 = (__hip_bfloat16*)(w + O_E4);

  VGNN_27049704030896_kernel<<<dim3((NN + 3) / 4, HH), 128, 0, stream>>>(
      embed, W_enc, a_esrc, a_edst, Wh, f1, f2, ef1hi, ef1lo);
  k_rankw2<<<48, 128, 0, stream>>>(f2, f1, W_dec, a_ddst,
                                   jsort, elo, ehi, pstar, w2);
  k_scan<<<BB * HH * 2, 1024, 0, stream>>>(data, jsort, elo, ehi, Wh,
                                           SnapLo, SnapHi, SnapLoS, SnapHiS);
  k_row <<<dim3(LL / 4, BB), 256, 0, stream>>>(data, Wh, pstar, jsort, elo, ehi,
                                               ef1hi, ef1lo, SnapLo, SnapHi,
                                               SnapLoS, SnapHiS, g_enc, b_enc, w2,
                                               enc4, wrow);
  k_acc <<<dim3(32, BB), 256, 0, stream>>>(data, enc4, wrow, Upart);
  k_fin <<<BB, 1024, 0, stream>>>(Upart, wrow, W_dec,
                                  g_dec, b_dec, V_w, V_b,
                                  o1_w, o1_b, o2_w, o2_b, out);
}